// Round 11
// baseline (4001.793 us; speedup 1.0000x reference)
//
#include <hip/hip_runtime.h>
#include <stdint.h>

// Problem constants
constexpr int T_STEPS = 512;
constexpr int BSZ     = 256;
constexpr int OBSD    = 64;
constexpr int HID     = 512;
constexpr int NROWS   = T_STEPS * BSZ;   // 131072

// LSTM partitioning: 16 groups x 16 WGs. Group owns 16 batch rows; WG owns
// 32 h-cols. Wave q of a WG computes ALL 4 gates for 8 cols (gate-pair
// fragments) and stages h cols 128q..128q+127 (col-sliced consumption).
constexpr int GROUPS = 16;
constexpr int WPG    = 16;
constexpr int BW     = 16;

typedef __attribute__((ext_vector_type(8))) short bf16x8;
typedef __attribute__((ext_vector_type(4))) float f32x4;

__device__ __forceinline__ float bf2f(uint16_t u) {
  union { uint32_t i; float f; } v; v.i = ((uint32_t)u) << 16; return v.f;
}
__device__ __forceinline__ uint16_t f2bf(float f) {
  union { float f; uint32_t i; } v; v.f = f;
  return (uint16_t)((v.i + 0x7FFFu + ((v.i >> 16) & 1u)) >> 16);
}
__device__ __forceinline__ uint64_t pack4(float a, float b, float c, float d) {
  uint32_t lo = (uint32_t)f2bf(a) | ((uint32_t)f2bf(b) << 16);
  uint32_t hi = (uint32_t)f2bf(c) | ((uint32_t)f2bf(d) << 16);
  return (uint64_t)lo | ((uint64_t)hi << 32);
}
__device__ __forceinline__ float sigm(float x) { return 1.f / (1.f + __expf(-x)); }
__device__ __forceinline__ float tanh_fast(float x) {
  float e = __expf(2.f * x);
  return 1.f - 2.f / (e + 1.f);
}

__device__ __forceinline__ void gll16(const void* g, void* l) {
  __builtin_amdgcn_global_load_lds(
      (const __attribute__((address_space(1))) uint32_t*)g,
      (__attribute__((address_space(3))) uint32_t*)l, 16, 0, 0);
}

// ---------------------------------------------------------------------------
// Persistent LSTM scan. 256 blocks x 256 threads, 1 block/CU.
// Transport: round-5 proven agent-scope (LIC) protocol (sc0/XCD-L2 tested
// rounds 6-9: 2.5x slower regardless of discipline -> closed).
// Round-11 structure: ONE barrier per step.
//  - Ab double-buffered by t-parity: stage(t+1) never races MFMA(t).
//  - Wave q = all 4 gates x 8 cols via paired B-fragments
//    (frag0 = [I cols0-7 | F cols0-7], frag1 = [G | O]); the I/F and G/O
//    values for a cell sit in lanes l and l^8 -> shfl_xor(8) exchange,
//    cell update wave-local (paired lanes redundantly compute identical
//    cells). No gl LDS, no second barrier.
//  - Wave q stages h cols 128q..128q+127 (all 16 rows) -> depends on exactly
//    16 producer waves; flags win-major so the poll is one 64B read:
//    consumer wave q polls flg[g*64 + 16q + 0..15].
// LDS: Ab 2 x 16 x 1152 = 36864 B.
// ---------------------------------------------------------------------------
__global__ __launch_bounds__(256, 1) void lstm_kernel(
    const float* __restrict__ xin, const float* __restrict__ done,
    const float* __restrict__ h0, const float* __restrict__ c0,
    const float* __restrict__ W_ih, const float* __restrict__ W_hh,
    const float* __restrict__ b_ih, const float* __restrict__ b_hh,
    uint16_t* __restrict__ hs, uint32_t* __restrict__ flg,
    float* __restrict__ out)
{
  __shared__ char Ab[2 * 16 * 1152];

  const int wg   = blockIdx.x;
  const int g    = wg >> 4;         // group
  const int win  = wg & 15;         // slot within group -> col block win*32
  const int bg   = g * BW;
  const int tid  = threadIdx.x;
  const int lane = tid & 63;
  const int q    = tid >> 6;        // wave id
  const int nl   = lane & 15;
  const int lg   = lane >> 4;       // lane group -> batch rows lg*4..lg*4+3

  // one-time: drop stale cache lines from a previous graph replay
  __builtin_amdgcn_fence(__ATOMIC_ACQUIRE, "agent");

  // ---- weights into VGPRs: gate-pair fragments ----
  // frag0: nl<8 -> I-gate col 8q+nl ; nl>=8 -> F-gate col 8q+nl-8
  // frag1: nl<8 -> G-gate          ; nl>=8 -> O-gate
  const int c_l = win * 32 + q * 8 + (lane & 7);   // this lane's hidden col
  bf16x8 bq0[18], bq1[18];
  {
    const int col  = win * 32 + q * 8 + (nl & 7);
    const int r0   = ((nl < 8) ? 0 : 1) * 512 + col;
    const int r1   = ((nl < 8) ? 2 : 3) * 512 + col;
    const int kg8  = (lane >> 4) * 8;
    #pragma unroll
    for (int ks = 0; ks < 18; ++ks) {
      const float* s0 = (ks < 16)
          ? (W_hh + (size_t)r0 * 512 + ks * 32 + kg8)
          : (W_ih + (size_t)r0 * 64 + (ks - 16) * 32 + kg8);
      const float* s1 = (ks < 16)
          ? (W_hh + (size_t)r1 * 512 + ks * 32 + kg8)
          : (W_ih + (size_t)r1 * 64 + (ks - 16) * 32 + kg8);
      float4 a0 = *(const float4*)s0;
      float4 a1 = *(const float4*)(s0 + 4);
      float4 b0 = *(const float4*)s1;
      float4 b1 = *(const float4*)(s1 + 4);
      bf16x8 va, vb;
      va[0] = (short)f2bf(a0.x); va[1] = (short)f2bf(a0.y);
      va[2] = (short)f2bf(a0.z); va[3] = (short)f2bf(a0.w);
      va[4] = (short)f2bf(a1.x); va[5] = (short)f2bf(a1.y);
      va[6] = (short)f2bf(a1.z); va[7] = (short)f2bf(a1.w);
      vb[0] = (short)f2bf(b0.x); vb[1] = (short)f2bf(b0.y);
      vb[2] = (short)f2bf(b0.z); vb[3] = (short)f2bf(b0.w);
      vb[4] = (short)f2bf(b1.x); vb[5] = (short)f2bf(b1.y);
      vb[6] = (short)f2bf(b1.z); vb[7] = (short)f2bf(b1.w);
      bq0[ks] = va; bq1[ks] = vb;
    }
  }
  // biases for this lane's col (all 4 gates)
  const float bI = b_ih[0 * 512 + c_l] + b_hh[0 * 512 + c_l];
  const float bF = b_ih[1 * 512 + c_l] + b_hh[1 * 512 + c_l];
  const float bG = b_ih[2 * 512 + c_l] + b_hh[2 * 512 + c_l];
  const float bO = b_ih[3 * 512 + c_l] + b_hh[3 * 512 + c_l];

  // c-state: rows lg*4+reg, col c_l (paired lanes hold identical copies)
  float creg[4];
  #pragma unroll
  for (int reg = 0; reg < 4; ++reg)
    creg[reg] = c0[(size_t)(bg + lg * 4 + reg) * 512 + c_l];

  const int sr  = tid >> 4;          // x staging row (0..15)
  const int sc4 = (tid & 15) * 4;    // x col base (4 floats/thread)

  __syncthreads();

  for (int t = 0; t < T_STEPS; ++t) {
    char* buf = Ab + (t & 1) * 18432;

    // ---- hoisted loads (overlap the poll): x_t, done row values ----
    const float* xp = xin + ((size_t)t * BSZ + bg + sr) * OBSD + sc4;
    float4 xa = *(const float4*)xp;
    float dv = (lane < 16) ? done[(size_t)t * BSZ + bg + lane] : 0.f;

    // stage x_t into buf (last read of buf was MFMA(t-2), before barrier(t-1))
    *(uint64_t*)(buf + ((sr * 1152 + 1024 + sc4 * 2) ^ ((sr & 7) << 4))) =
        pack4(xa.x, xa.y, xa.z, xa.w);

    // ---- wave q waits for its 16 producer waves (cols 128q..128q+127) ----
    if (t > 0) {
      for (;;) {
        uint32_t f = (lane < WPG)
            ? __hip_atomic_load(flg + g * 64 + 16 * q + lane,
                                __ATOMIC_RELAXED, __HIP_MEMORY_SCOPE_AGENT)
            : 0xFFFFFFFFu;
        if (__all((int)(f >= (uint32_t)t))) break;
        __builtin_amdgcn_s_sleep(1);
      }
      __builtin_amdgcn_fence(__ATOMIC_ACQUIRE, "workgroup");
    }

    // ---- stage h_{t-1} cols 128q..128q+127, all 16 rows ----
    if (t == 0) {
      #pragma unroll
      for (int r = 0; r < 16; ++r) {
        float rstm = (__shfl(dv, r) > 0.5f) ? 0.f : 1.f;
        const float* hp = h0 + (size_t)(bg + r) * 512 + 128 * q + lane * 2;
        float2 hv2 = *(const float2*)hp;
        uint32_t v = (uint32_t)f2bf(hv2.x * rstm) |
                     ((uint32_t)f2bf(hv2.y * rstm) << 16);
        *(uint32_t*)(buf + ((r * 1152 + 256 * q + lane * 4) ^ ((r & 7) << 4))) = v;
      }
    } else {
      #pragma unroll
      for (int r = 0; r < 16; ++r) {
        const uint32_t* hrow =
            (const uint32_t*)(hs + ((size_t)(t - 1) * BSZ + bg + r) * 512);
        uint32_t v = __hip_atomic_load(hrow + 64 * q + lane,
                                       __ATOMIC_RELAXED, __HIP_MEMORY_SCOPE_AGENT);
        if (__shfl(dv, r) > 0.5f) v = 0;
        *(uint32_t*)(buf + ((r * 1152 + 256 * q + lane * 4) ^ ((r & 7) << 4))) = v;
      }
    }
    __syncthreads();   // the ONLY barrier per step

    // ---- MFMA: [16 rows x 16 cols] x 2 fragments, K=576 ----
    f32x4 ac0 = {0.f, 0.f, 0.f, 0.f};
    f32x4 ac1 = {0.f, 0.f, 0.f, 0.f};
    {
      const int ar = lane & 15;
      const int kg = lane >> 4;
      #pragma unroll
      for (int ks = 0; ks < 18; ++ks) {
        int kb = ks * 64 + kg * 16;
        bf16x8 a = *(const bf16x8*)(buf + ((ar * 1152 + kb) ^ ((ar & 7) << 4)));
        ac0 = __builtin_amdgcn_mfma_f32_16x16x32_bf16(a, bq0[ks], ac0, 0, 0, 0);
        ac1 = __builtin_amdgcn_mfma_f32_16x16x32_bf16(a, bq1[ks], ac1, 0, 0, 0);
      }
    }

    // ---- shfl gate exchange + wave-local cell update ----
    float hv[4];
    #pragma unroll
    for (int reg = 0; reg < 4; ++reg) {
      float own0 = ac0[reg], own1 = ac1[reg];
      float oth0 = __shfl_xor(own0, 8);
      float oth1 = __shfl_xor(own1, 8);
      float I = ((nl < 8) ? own0 : oth0) + bI;
      float F = ((nl < 8) ? oth0 : own0) + bF;
      float G = ((nl < 8) ? own1 : oth1) + bG;
      float O = ((nl < 8) ? oth1 : own1) + bO;
      float dcell = __shfl(dv, lg * 4 + reg);
      float m = dcell > 0.5f ? 0.f : 1.f;
      float cc = creg[reg] * m;
      cc = sigm(F) * cc + sigm(I) * tanh_fast(G);
      creg[reg] = cc;
      hv[reg] = sigm(O) * tanh_fast(cc);
    }
    // ---- h store (lanes nl<8 only; paired lanes hold identical values) ----
    if (nl < 8) {
      #pragma unroll
      for (int reg = 0; reg < 4; ++reg) {
        uint16_t* hp = hs + ((size_t)t * BSZ + bg + lg * 4 + reg) * 512 + c_l;
        __hip_atomic_store((uint16_t*)hp, f2bf(hv[reg]),
                           __ATOMIC_RELAXED, __HIP_MEMORY_SCOPE_AGENT);
      }
      if (t == T_STEPS - 1) {
        #pragma unroll
        for (int reg = 0; reg < 4; ++reg) {
          size_t ob = (size_t)(bg + lg * 4 + reg) * 512 + c_l;
          out[NROWS + ob]     = hv[reg];
          out[2 * NROWS + ob] = creg[reg];
        }
      }
    }
    // per-wave flag: own h stores drained at the LIC -> publish
    asm volatile("s_waitcnt vmcnt(0)" ::: "memory");
    if (lane == 0)
      __hip_atomic_store(flg + g * 64 + win * 4 + q, (uint32_t)(t + 1),
                         __ATOMIC_RELAXED, __HIP_MEMORY_SCOPE_AGENT);
  }
}

// ---------------------------------------------------------------------------
// Per-row LayerNorm stats from bf16 hidden: rstd[m], murs[m] = mu*rstd.
// ---------------------------------------------------------------------------
__global__ void ln_stats_kernel(const uint16_t* __restrict__ hsrc,
                                float* __restrict__ rstd_a, float* __restrict__ murs_a)
{
  const int lane = threadIdx.x & 63;
  const size_t row = (size_t)blockIdx.x * 4 + (threadIdx.x >> 6);
  bf16x8 v = *(const bf16x8*)(hsrc + row * 512 + lane * 8);
  float s = 0.f, s2 = 0.f;
  #pragma unroll
  for (int j = 0; j < 8; ++j) { float f = bf2f((uint16_t)v[j]); s += f; s2 += f * f; }
  #pragma unroll
  for (int o = 1; o < 64; o <<= 1) { s += __shfl_xor(s, o); s2 += __shfl_xor(s2, o); }
  if (lane == 0) {
    float mu  = s * (1.f / 512.f);
    float var = s2 * (1.f / 512.f) - mu * mu;
    float rs  = rsqrtf(var + 1e-5f);
    rstd_a[row] = rs;
    murs_a[row] = mu * rs;
  }
}

// ---------------------------------------------------------------------------
// u[n] = sum_k ln_b[k]*W1[n,k] + b1[n] ;  v[n] = sum_k ln_g[k]*W1[n,k]
// ---------------------------------------------------------------------------
__global__ void uv_kernel(const float* __restrict__ W1, const float* __restrict__ ln_g,
                          const float* __restrict__ ln_b, const float* __restrict__ b1,
                          float* __restrict__ u, float* __restrict__ v)
{
  const int lane = threadIdx.x & 63;
  const int row  = blockIdx.x * 4 + (threadIdx.x >> 6);
  const float* wp = W1 + (size_t)row * 512 + lane * 8;
  float4 w0 = *(const float4*)wp;
  float4 w1 = *(const float4*)(wp + 4);
  float4 g0 = *(const float4*)(ln_g + lane * 8);
  float4 g1 = *(const float4*)(ln_g + lane * 8 + 4);
  float4 b0 = *(const float4*)(ln_b + lane * 8);
  float4 b1v = *(const float4*)(ln_b + lane * 8 + 4);
  float su = b0.x * w0.x + b0.y * w0.y + b0.z * w0.z + b0.w * w0.w
           + b1v.x * w1.x + b1v.y * w1.y + b1v.z * w1.z + b1v.w * w1.w;
  float sv = g0.x * w0.x + g0.y * w0.y + g0.z * w0.z + g0.w * w0.w
           + g1.x * w1.x + g1.y * w1.y + g1.z * w1.z + g1.w * w1.w;
  #pragma unroll
  for (int o = 1; o < 64; o <<= 1) { su += __shfl_xor(su, o); sv += __shfl_xor(sv, o); }
  if (lane == 0) { u[row] = su + b1[row]; v[row] = sv; }
}

// ---------------------------------------------------------------------------
// Fused GEMM: C = tanh(epilogue(A[64 rows, K=512] @ W[,512]^T))
// MODE 0: LN-affine epilogue  tanh(rstd_m*G - murs_m*v_n + u_n)   (u has +b1)
// MODE 1: bias epilogue       tanh(G + bias_n)
// ---------------------------------------------------------------------------
template<int MODE>
__global__ __launch_bounds__(256, 2) void gemm_fused(
    const uint16_t* __restrict__ Abase, const uint16_t* __restrict__ W,
    uint16_t* __restrict__ C, int ntiles,
    const float* __restrict__ rstd_a, const float* __restrict__ murs_a,
    const float* __restrict__ uvec, const float* __restrict__ vvec,
    const float* __restrict__ bias)
{
  __shared__ uint16_t At[64 * 512];   // 65536 B
  const int tid  = threadIdx.x;
  const int lane = tid & 63;
  const int wv   = tid >> 6;
  const size_t mbase = (size_t)blockIdx.x * 64;

  for (int r8 = 0; r8 < 16; ++r8) {
    int row = wv * 16 + r8;
    int sb  = (lane * 16) ^ ((row & 7) << 4);
    gll16(Abase + (mbase + row) * 512 + sb / 2, At + row * 512);
  }
  __syncthreads();

  const int fr = lane & 15, kg = lane >> 4;
  const int mloc = (wv & 1) * 32;
  const int nhalf = (wv >> 1) * 64;

  for (int nt = 0; nt < ntiles; ++nt) {
    const int nbase = nt * 128 + nhalf;
    f32x4 vz = {0.f, 0.f, 0.f, 0.f};
    f32x4 acc[4][2];
    #pragma unroll
    for (int i = 0; i < 4; ++i) { acc[i][0] = vz; acc[i][1] = vz; }

    #pragma unroll 4
    for (int kb = 0; kb < 16; ++kb) {
      const int ke = kb * 32 + kg * 8;
      bf16x8 wf[4];
      #pragma unroll
      for (int i = 0; i < 4; ++i)
        wf[i] = *(const bf16x8*)(W + (size_t)(nbase + i * 16 + fr) * 512 + ke);
      bf16x8 af[2];
      #pragma unroll
      for (int j = 0; j < 2; ++j) {
        int mr = mloc + j * 16 + fr;
        af[j] = *(const bf16x8*)((const char*)At + ((mr * 1024 + ke * 2) ^ ((mr & 7) << 4)));
      }
      #pragma unroll
      for (int i = 0; i < 4; ++i)
        #pragma unroll
        for (int j = 0; j < 2; ++j)
          acc[i][j] = __builtin_amdgcn_mfma_f32_16x16x32_bf16(wf[i], af[j], acc[i][j], 0, 0, 0);
    }

    #pragma unroll
    for (int j = 0; j < 2; ++j) {
      size_t m = mbase + mloc + j * 16 + fr;
      float rs = 0.f, mrs = 0.f;
      if constexpr (MODE == 0) { rs = rstd_a[m]; mrs = murs_a[m]; }
      #pragma unroll
      for (int i = 0; i < 4; ++i) {
        int n = nbase + i * 16 + kg * 4;
        float o0, o1, o2, o3;
        if constexpr (MODE == 0) {
          float4 uu = *(const float4*)(uvec + n);
          float4 vv = *(const float4*)(vvec + n);
          o0 = tanh_fast(rs * acc[i][j][0] - mrs * vv.x + uu.x);
          o1 = tanh_fast(rs * acc[i][j][1] - mrs * vv.y + uu.y);
          o2 = tanh_fast(rs * acc[i][j][2] - mrs * vv.z + uu.z);
          o3 = tanh_fast(rs * acc[i][j][3] - mrs * vv.w + uu.w);
        } else {
          float4 bb = *(const float4*)(bias + n);
          o0 = tanh_fast(acc[i][j][0] + bb.x);
          o1 = tanh_fast(acc[i][j][1] + bb.y);
          o2 = tanh_fast(acc[i][j][2] + bb.z);
          o3 = tanh_fast(acc[i][j][3] + bb.w);
        }
        uint32_t lo = (uint32_t)f2bf(o0) | ((uint32_t)f2bf(o1) << 16);
        uint32_t hi = (uint32_t)f2bf(o2) | ((uint32_t)f2bf(o3) << 16);
        *(uint64_t*)(C + m * 512 + n) = (uint64_t)lo | ((uint64_t)hi << 32);
      }
    }
    __syncthreads();
  }
}

// ---------------------------------------------------------------------------
// value[m] = a2[m,:256] . Wv + bv   (a2 at stride 512; one wave per row)
// ---------------------------------------------------------------------------
__global__ void gemv_kernel(const uint16_t* __restrict__ a2, const float* __restrict__ Wv,
                            const float* __restrict__ bv, float* __restrict__ outv)
{
  const int lane = threadIdx.x & 63;
  const size_t row = (size_t)blockIdx.x * 4 + (threadIdx.x >> 6);
  const uint16_t* p = a2 + row * 512 + lane * 4;
  uint64_t v = *(const uint64_t*)p;
  float4 w = *(const float4*)(Wv + lane * 4);
  float d = bf2f((uint16_t)(v & 0xFFFF)) * w.x
          + bf2f((uint16_t)((v >> 16) & 0xFFFF)) * w.y
          + bf2f((uint16_t)((v >> 32) & 0xFFFF)) * w.z
          + bf2f((uint16_t)((v >> 48) & 0xFFFF)) * w.w;
  #pragma unroll
  for (int o = 1; o < 64; o <<= 1) d += __shfl_xor(d, o);
  if (lane == 0) outv[row] = d + bv[0];
}

// ---------------------------------------------------------------------------
// W1 (fold ln_g into columns) then W2, fp32 -> bf16 contiguous.
// ---------------------------------------------------------------------------
__global__ void wconv_kernel(const float* __restrict__ W1, const float* __restrict__ W2,
                             const float* __restrict__ ln_g, uint16_t* __restrict__ dst)
{
  int idx = blockIdx.x * 256 + threadIdx.x;
  int i4 = idx * 4;
  float4 v;
  if (i4 < 262144) {
    v = *(const float4*)(W1 + i4);
    int c = i4 & 511;
    float4 gv = *(const float4*)(ln_g + c);
    v.x *= gv.x; v.y *= gv.y; v.z *= gv.z; v.w *= gv.w;
  } else {
    v = *(const float4*)(W2 + (i4 - 262144));
  }
  uint32_t lo = (uint32_t)f2bf(v.x) | ((uint32_t)f2bf(v.y) << 16);
  uint32_t hi = (uint32_t)f2bf(v.z) | ((uint32_t)f2bf(v.w) << 16);
  *(uint64_t*)(dst + i4) = (uint64_t)lo | ((uint64_t)hi << 32);
}

extern "C" void kernel_launch(void* const* d_in, const int* in_sizes, int n_in,
                              void* d_out, int out_size, void* d_ws, size_t ws_size,
                              hipStream_t stream)
{
  (void)in_sizes; (void)n_in;
  const float* x    = (const float*)d_in[0];
  const float* done = (const float*)d_in[1];
  const float* h0   = (const float*)d_in[2];
  const float* c0   = (const float*)d_in[3];
  const float* W_ih = (const float*)d_in[4];
  const float* W_hh = (const float*)d_in[5];
  const float* b_ih = (const float*)d_in[6];
  const float* b_hh = (const float*)d_in[7];
  const float* ln_g = (const float*)d_in[8];
  const float* ln_b = (const float*)d_in[9];
  const float* W1   = (const float*)d_in[10];
  const float* b1   = (const float*)d_in[11];
  const float* W2   = (const float*)d_in[12];
  const float* b2   = (const float*)d_in[13];
  const float* Wv   = (const float*)d_in[14];
  const float* bv   = (const float*)d_in[15];
  float* out = (float*)d_out;
  char* ws = (char*)d_ws;

  // ws layout (bytes):
  //   0        flg      4096     (16 groups x 64 per-wave flags, 256B/group)
  //   16384    wbf      786432   (bf16 W1g | W2)
  //   802816   u,v      4096     (512 f32 each)
  //   806912   rstd     524288
  //   1331200  murs     524288
  //   2097152  hs       134217728  (bf16 [T*B,512]; later a1 in-place, a2 cols 0..255)
  constexpr size_t NEED = 2097152ULL + 134217728ULL;
  if (ws_size < NEED) {
    hipMemsetAsync(d_out, 0, (size_t)out_size * 4, stream);
    return;
  }
  uint32_t* flg  = (uint32_t*)ws;
  uint16_t* wbf  = (uint16_t*)(ws + 16384);
  float*    uv_u = (float*)(ws + 802816);
  float*    uv_v = (float*)(ws + 802816 + 2048);
  float*    rstd = (float*)(ws + 806912);
  float*    murs = (float*)(ws + 1331200);
  uint16_t* hsb  = (uint16_t*)(ws + 2097152);

  hipMemsetAsync(ws, 0, 16384, stream);
  hipLaunchKernelGGL(wconv_kernel, dim3(384), dim3(256), 0, stream, W1, W2, ln_g, wbf);
  hipLaunchKernelGGL(uv_kernel, dim3(128), dim3(256), 0, stream, W1, ln_g, ln_b, b1, uv_u, uv_v);
  hipLaunchKernelGGL(lstm_kernel, dim3(256), dim3(256), 0, stream,
                     x, done, h0, c0, W_ih, W_hh, b_ih, b_hh, hsb, flg, out);
  hipLaunchKernelGGL(ln_stats_kernel, dim3(32768), dim3(256), 0, stream, hsb, rstd, murs);
  // GEMM1: a1 = tanh(LN(h) @ W1^T + b1), in-place over hs
  hipLaunchKernelGGL((gemm_fused<0>), dim3(2048), dim3(256), 0, stream,
                     hsb, wbf, hsb, 4, rstd, murs, uv_u, uv_v, (const float*)nullptr);
  // GEMM2: a2 = tanh(a1 @ W2^T + b2), in-place over hs cols [0,256)
  hipLaunchKernelGGL((gemm_fused<1>), dim3(2048), dim3(256), 0, stream,
                     hsb, wbf + 262144, hsb, 2,
                     (const float*)nullptr, (const float*)nullptr,
                     (const float*)nullptr, (const float*)nullptr, b2);
  hipLaunchKernelGGL(gemv_kernel, dim3(32768), dim3(256), 0, stream, hsb, Wv, bv, out);
}

// Round 12
// 1964.718 us; speedup vs baseline: 2.0368x; 2.0368x over previous
//
#include <hip/hip_runtime.h>
#include <stdint.h>

// Problem constants
constexpr int T_STEPS = 512;
constexpr int BSZ     = 256;
constexpr int OBSD    = 64;
constexpr int HID     = 512;
constexpr int NROWS   = T_STEPS * BSZ;   // 131072

// LSTM partitioning: 16 groups x 16 WGs. Group owns 16 batch rows; WG owns
// 32 h-cols (all 4 gates). g = wg & 15 -> under round-robin dispatch all 16
// members of a group share one XCD (performance-only assumption: wrong
// mapping just lowers L2 hit rate, correctness unaffected).
constexpr int GROUPS = 16;
constexpr int WPG    = 16;
constexpr int BW     = 16;

typedef __attribute__((ext_vector_type(8))) short bf16x8;
typedef __attribute__((ext_vector_type(4))) float f32x4;

__device__ __forceinline__ float bf2f(uint16_t u) {
  union { uint32_t i; float f; } v; v.i = ((uint32_t)u) << 16; return v.f;
}
__device__ __forceinline__ uint16_t f2bf(float f) {
  union { float f; uint32_t i; } v; v.f = f;
  return (uint16_t)((v.i + 0x7FFFu + ((v.i >> 16) & 1u)) >> 16);
}
__device__ __forceinline__ uint64_t pack4(float a, float b, float c, float d) {
  uint32_t lo = (uint32_t)f2bf(a) | ((uint32_t)f2bf(b) << 16);
  uint32_t hi = (uint32_t)f2bf(c) | ((uint32_t)f2bf(d) << 16);
  return (uint64_t)lo | ((uint64_t)hi << 32);
}
__device__ __forceinline__ float sigm(float x) { return 1.f / (1.f + __expf(-x)); }
__device__ __forceinline__ float tanh_fast(float x) {
  float e = __expf(2.f * x);
  return 1.f - 2.f / (e + 1.f);
}

__device__ __forceinline__ void gll16(const void* g, void* l) {
  __builtin_amdgcn_global_load_lds(
      (const __attribute__((address_space(1))) uint32_t*)g,
      (__attribute__((address_space(3))) uint32_t*)l, 16, 0, 0);
}

// ---------------------------------------------------------------------------
// Persistent LSTM scan. 256 blocks x 256 threads, 1 block/CU.
// == Round-10 kernel (proven 1.90 ms) with ONE mechanism changed:
// h-exchange LOADS are now plain cacheable loads (L1/L2), not sc1.
// Safety: every hs[t] address is written exactly once per dispatch (sc1,
// LIC) and read only after the producer's flag -> an L2/L1 fill is always
// post-write; previous-replay lines are dropped by the start-of-kernel
// agent-acquire (buffer_inv); t-stride (256KB) and row-stride (1KB) are
// 128B-aligned so no cache line spans a write/read epoch boundary.
// Flags stay agent-scope sc1 (polling cached flags would spin stale).
// Round-11's shfl/gate-pair restructure REVERTED (2B scattered h-stores
// doubled WRITE_SIZE -> 1.9x regression).
// ---------------------------------------------------------------------------
__global__ __launch_bounds__(256, 1) void lstm_kernel(
    const float* __restrict__ xin, const float* __restrict__ done,
    const float* __restrict__ h0, const float* __restrict__ c0,
    const float* __restrict__ W_ih, const float* __restrict__ W_hh,
    const float* __restrict__ b_ih, const float* __restrict__ b_hh,
    uint16_t* __restrict__ hs, uint32_t* __restrict__ flg,
    float* __restrict__ out)
{
  __shared__ char  Ab[16 * 1152];
  __shared__ float gl[4 * 528];     // [gate][16 rows][33 pad]
  __shared__ float bl[128];         // [gate][32 cols]

  const int wg   = blockIdx.x;
  const int g    = wg & 15;         // group (co-resident per XCD if round-robin)
  const int win  = wg >> 4;         // slot within group -> col block win*32
  const int bg   = g * BW;
  const int tid  = threadIdx.x;
  const int lane = tid & 63;
  const int q    = tid >> 6;        // wave id == gate id

  // one-time: drop stale cache lines from a previous graph replay
  __builtin_amdgcn_fence(__ATOMIC_ACQUIRE, "agent");

  // ---- weights into VGPRs: wave q = gate q, col frags f0=cols 0-15, f1=16-31
  bf16x8 bq0[18], bq1[18];
  {
    const int r0  = q * 512 + win * 32 + (lane & 15);
    const int r1  = r0 + 16;
    const int kg8 = (lane >> 4) * 8;
    #pragma unroll
    for (int ks = 0; ks < 18; ++ks) {
      const float* s0 = (ks < 16)
          ? (W_hh + (size_t)r0 * 512 + ks * 32 + kg8)
          : (W_ih + (size_t)r0 * 64 + (ks - 16) * 32 + kg8);
      const float* s1 = (ks < 16)
          ? (W_hh + (size_t)r1 * 512 + ks * 32 + kg8)
          : (W_ih + (size_t)r1 * 64 + (ks - 16) * 32 + kg8);
      float4 a0 = *(const float4*)s0;
      float4 a1 = *(const float4*)(s0 + 4);
      float4 b0 = *(const float4*)s1;
      float4 b1 = *(const float4*)(s1 + 4);
      bf16x8 va, vb;
      va[0] = (short)f2bf(a0.x); va[1] = (short)f2bf(a0.y);
      va[2] = (short)f2bf(a0.z); va[3] = (short)f2bf(a0.w);
      va[4] = (short)f2bf(a1.x); va[5] = (short)f2bf(a1.y);
      va[6] = (short)f2bf(a1.z); va[7] = (short)f2bf(a1.w);
      vb[0] = (short)f2bf(b0.x); vb[1] = (short)f2bf(b0.y);
      vb[2] = (short)f2bf(b0.z); vb[3] = (short)f2bf(b0.w);
      vb[4] = (short)f2bf(b1.x); vb[5] = (short)f2bf(b1.y);
      vb[6] = (short)f2bf(b1.z); vb[7] = (short)f2bf(b1.w);
      bq0[ks] = va; bq1[ks] = vb;
    }
  }
  if (tid < 128) {
    int gq = tid >> 5, c = tid & 31;
    int grow = gq * 512 + win * 32 + c;
    bl[tid] = b_ih[grow] + b_hh[grow];
  }

  const int b_loc = tid >> 4;        // 0..15 (batch row within group)
  const int n0    = (tid & 15) * 2;  // col pair within WG's 32 cols
  float creg0 = c0[(size_t)(bg + b_loc) * HID + win * 32 + n0];
  float creg1 = c0[(size_t)(bg + b_loc) * HID + win * 32 + n0 + 1];

  const int sr  = tid >> 4;          // x staging row (0..15)
  const int sc4 = (tid & 15) * 4;    // x col base (4 floats/thread)
  const int rw  = q * 4;             // wave's 4 h rows (produce AND consume)

  __syncthreads();

  for (int t = 0; t < T_STEPS; ++t) {
    // ---- hoisted loads (overlap the poll): x_t, done values ----
    const float* xp = xin + ((size_t)t * BSZ + bg + sr) * OBSD + sc4;
    float4 xa = *(const float4*)xp;
    float dvs[4];
    #pragma unroll
    for (int r8 = 0; r8 < 4; ++r8)
      dvs[r8] = done[(size_t)t * BSZ + bg + rw + r8];
    float dv_b = done[(size_t)t * BSZ + bg + b_loc];

    // stage x_t into Ab
    *(uint64_t*)(Ab + ((sr * 1152 + 1024 + sc4 * 2) ^ ((sr & 7) << 4))) =
        pack4(xa.x, xa.y, xa.z, xa.w);

    // ---- wave q waits for its 16 producer-wave-q flags (step t-1) ----
    if (t > 0) {
      for (;;) {
        uint32_t f = (lane < WPG)
            ? __hip_atomic_load(flg + g * 64 + lane * 4 + q,
                                __ATOMIC_RELAXED, __HIP_MEMORY_SCOPE_AGENT)
            : 0xFFFFFFFFu;
        if (__all((int)(f >= (uint32_t)t))) break;
        __builtin_amdgcn_s_sleep(1);
      }
      __builtin_amdgcn_fence(__ATOMIC_ACQUIRE, "workgroup");
    }

    // ---- stage h_{t-1} rows rw..rw+3 (plain cacheable, 1KB per instr) ----
    if (t == 0) {
      #pragma unroll
      for (int r8 = 0; r8 < 4; ++r8) {
        int r = rw + r8;
        uint64_t v0 = 0, v1 = 0;
        if (dvs[r8] <= 0.5f) {
          const float* hp = h0 + (size_t)(bg + r) * HID;
          float4 ha = *(const float4*)(hp + lane * 4);
          float4 hb = *(const float4*)(hp + 256 + lane * 4);
          v0 = pack4(ha.x, ha.y, ha.z, ha.w);
          v1 = pack4(hb.x, hb.y, hb.z, hb.w);
        }
        *(uint64_t*)(Ab + ((r * 1152 + lane * 8) ^ ((r & 7) << 4))) = v0;
        *(uint64_t*)(Ab + ((r * 1152 + 512 + lane * 8) ^ ((r & 7) << 4))) = v1;
      }
    } else {
      #pragma unroll
      for (int r8 = 0; r8 < 4; ++r8) {
        int r = rw + r8;
        const uint4* hrow =
            (const uint4*)(hs + ((size_t)(t - 1) * BSZ + bg + r) * 512);
        uint4 v = hrow[lane];               // plain load: L1/L2-cacheable
        if (dvs[r8] > 0.5f) { v.x = 0; v.y = 0; v.z = 0; v.w = 0; }
        *(uint4*)(Ab + ((r * 1152 + lane * 16) ^ ((r & 7) << 4))) = v;
      }
    }
    __syncthreads();   // barrier 1: all 16 rows staged

    // ---- MFMA: wave q -> gate q, [16 rows x 32 cols], K=576 ----
    f32x4 ac0 = {0.f, 0.f, 0.f, 0.f};
    f32x4 ac1 = {0.f, 0.f, 0.f, 0.f};
    {
      const int ar = lane & 15;
      const int kg = lane >> 4;
      #pragma unroll
      for (int ks = 0; ks < 18; ++ks) {
        int kb = (ks * 32 + kg * 8) * 2;
        bf16x8 a = *(const bf16x8*)(Ab + ((ar * 1152 + kb) ^ ((ar & 7) << 4)));
        ac0 = __builtin_amdgcn_mfma_f32_16x16x32_bf16(a, bq0[ks], ac0, 0, 0, 0);
        ac1 = __builtin_amdgcn_mfma_f32_16x16x32_bf16(a, bq1[ks], ac1, 0, 0, 0);
      }
    }
    // ---- gates -> LDS exchange (rows padded to 33 words) ----
    {
      int c  = lane & 15;
      int rb = (lane >> 4) * 4;
      #pragma unroll
      for (int r = 0; r < 4; ++r) {
        gl[q * 528 + (rb + r) * 33 + c]      = ac0[r];
        gl[q * 528 + (rb + r) * 33 + 16 + c] = ac1[r];
      }
    }
    __syncthreads();   // barrier 2: all 4 gates exchanged

    // ---- cell update (c lives in registers across all 512 steps) ----
    {
      float m = dv_b > 0.5f ? 0.f : 1.f;
      float h0v, h1v;
      {
        float I = gl[b_loc * 33 + n0]          + bl[n0];
        float F = gl[528 + b_loc * 33 + n0]    + bl[32 + n0];
        float G = gl[1056 + b_loc * 33 + n0]   + bl[64 + n0];
        float O = gl[1584 + b_loc * 33 + n0]   + bl[96 + n0];
        float cc = creg0 * m;
        cc = sigm(F) * cc + sigm(I) * tanh_fast(G);
        creg0 = cc;
        h0v = sigm(O) * tanh_fast(cc);
      }
      {
        int n1 = n0 + 1;
        float I = gl[b_loc * 33 + n1]          + bl[n1];
        float F = gl[528 + b_loc * 33 + n1]    + bl[32 + n1];
        float G = gl[1056 + b_loc * 33 + n1]   + bl[64 + n1];
        float O = gl[1584 + b_loc * 33 + n1]   + bl[96 + n1];
        float cc = creg1 * m;
        cc = sigm(F) * cc + sigm(I) * tanh_fast(G);
        creg1 = cc;
        h1v = sigm(O) * tanh_fast(cc);
      }
      uint32_t pk = (uint32_t)f2bf(h0v) | ((uint32_t)f2bf(h1v) << 16);
      uint32_t* hp = (uint32_t*)(hs + ((size_t)t * BSZ + bg + b_loc) * HID + win * 32 + n0);
      __hip_atomic_store(hp, pk, __ATOMIC_RELAXED, __HIP_MEMORY_SCOPE_AGENT);
      if (t == T_STEPS - 1) {
        size_t ob = (size_t)(bg + b_loc) * HID + win * 32 + n0;
        out[NROWS + ob]         = h0v;
        out[NROWS + ob + 1]     = h1v;
        out[2 * NROWS + ob]     = creg0;
        out[2 * NROWS + ob + 1] = creg1;
      }
    }
    // per-wave flag: own h stores drained at the LIC -> publish immediately
    asm volatile("s_waitcnt vmcnt(0)" ::: "memory");
    if ((tid & 63) == 0)
      __hip_atomic_store(flg + g * 64 + win * 4 + q, (uint32_t)(t + 1),
                         __ATOMIC_RELAXED, __HIP_MEMORY_SCOPE_AGENT);
  }
}

// ---------------------------------------------------------------------------
// Per-row LayerNorm stats from bf16 hidden: rstd[m], murs[m] = mu*rstd.
// ---------------------------------------------------------------------------
__global__ void ln_stats_kernel(const uint16_t* __restrict__ hsrc,
                                float* __restrict__ rstd_a, float* __restrict__ murs_a)
{
  const int lane = threadIdx.x & 63;
  const size_t row = (size_t)blockIdx.x * 4 + (threadIdx.x >> 6);
  bf16x8 v = *(const bf16x8*)(hsrc + row * 512 + lane * 8);
  float s = 0.f, s2 = 0.f;
  #pragma unroll
  for (int j = 0; j < 8; ++j) { float f = bf2f((uint16_t)v[j]); s += f; s2 += f * f; }
  #pragma unroll
  for (int o = 1; o < 64; o <<= 1) { s += __shfl_xor(s, o); s2 += __shfl_xor(s2, o); }
  if (lane == 0) {
    float mu  = s * (1.f / 512.f);
    float var = s2 * (1.f / 512.f) - mu * mu;
    float rs  = rsqrtf(var + 1e-5f);
    rstd_a[row] = rs;
    murs_a[row] = mu * rs;
  }
}

// ---------------------------------------------------------------------------
// u[n] = sum_k ln_b[k]*W1[n,k] + b1[n] ;  v[n] = sum_k ln_g[k]*W1[n,k]
// ---------------------------------------------------------------------------
__global__ void uv_kernel(const float* __restrict__ W1, const float* __restrict__ ln_g,
                          const float* __restrict__ ln_b, const float* __restrict__ b1,
                          float* __restrict__ u, float* __restrict__ v)
{
  const int lane = threadIdx.x & 63;
  const int row  = blockIdx.x * 4 + (threadIdx.x >> 6);
  const float* wp = W1 + (size_t)row * 512 + lane * 8;
  float4 w0 = *(const float4*)wp;
  float4 w1 = *(const float4*)(wp + 4);
  float4 g0 = *(const float4*)(ln_g + lane * 8);
  float4 g1 = *(const float4*)(ln_g + lane * 8 + 4);
  float4 b0 = *(const float4*)(ln_b + lane * 8);
  float4 b1v = *(const float4*)(ln_b + lane * 8 + 4);
  float su = b0.x * w0.x + b0.y * w0.y + b0.z * w0.z + b0.w * w0.w
           + b1v.x * w1.x + b1v.y * w1.y + b1v.z * w1.z + b1v.w * w1.w;
  float sv = g0.x * w0.x + g0.y * w0.y + g0.z * w0.z + g0.w * w0.w
           + g1.x * w1.x + g1.y * w1.y + g1.z * w1.z + g1.w * w1.w;
  #pragma unroll
  for (int o = 1; o < 64; o <<= 1) { su += __shfl_xor(su, o); sv += __shfl_xor(sv, o); }
  if (lane == 0) { u[row] = su + b1[row]; v[row] = sv; }
}

// ---------------------------------------------------------------------------
// Fused GEMM: C = tanh(epilogue(A[64 rows, K=512] @ W[,512]^T))
// MODE 0: LN-affine epilogue  tanh(rstd_m*G - murs_m*v_n + u_n)   (u has +b1)
// MODE 1: bias epilogue       tanh(G + bias_n)
// ---------------------------------------------------------------------------
template<int MODE>
__global__ __launch_bounds__(256, 2) void gemm_fused(
    const uint16_t* __restrict__ Abase, const uint16_t* __restrict__ W,
    uint16_t* __restrict__ C, int ntiles,
    const float* __restrict__ rstd_a, const float* __restrict__ murs_a,
    const float* __restrict__ uvec, const float* __restrict__ vvec,
    const float* __restrict__ bias)
{
  __shared__ uint16_t At[64 * 512];   // 65536 B
  const int tid  = threadIdx.x;
  const int lane = tid & 63;
  const int wv   = tid >> 6;
  const size_t mbase = (size_t)blockIdx.x * 64;

  for (int r8 = 0; r8 < 16; ++r8) {
    int row = wv * 16 + r8;
    int sb  = (lane * 16) ^ ((row & 7) << 4);
    gll16(Abase + (mbase + row) * 512 + sb / 2, At + row * 512);
  }
  __syncthreads();

  const int fr = lane & 15, kg = lane >> 4;
  const int mloc = (wv & 1) * 32;
  const int nhalf = (wv >> 1) * 64;

  for (int nt = 0; nt < ntiles; ++nt) {
    const int nbase = nt * 128 + nhalf;
    f32x4 vz = {0.f, 0.f, 0.f, 0.f};
    f32x4 acc[4][2];
    #pragma unroll
    for (int i = 0; i < 4; ++i) { acc[i][0] = vz; acc[i][1] = vz; }

    #pragma unroll 4
    for (int kb = 0; kb < 16; ++kb) {
      const int ke = kb * 32 + kg * 8;
      bf16x8 wf[4];
      #pragma unroll
      for (int i = 0; i < 4; ++i)
        wf[i] = *(const bf16x8*)(W + (size_t)(nbase + i * 16 + fr) * 512 + ke);
      bf16x8 af[2];
      #pragma unroll
      for (int j = 0; j < 2; ++j) {
        int mr = mloc + j * 16 + fr;
        af[j] = *(const bf16x8*)((const char*)At + ((mr * 1024 + ke * 2) ^ ((mr & 7) << 4)));
      }
      #pragma unroll
      for (int i = 0; i < 4; ++i)
        #pragma unroll
        for (int j = 0; j < 2; ++j)
          acc[i][j] = __builtin_amdgcn_mfma_f32_16x16x32_bf16(wf[i], af[j], acc[i][j], 0, 0, 0);
    }

    #pragma unroll
    for (int j = 0; j < 2; ++j) {
      size_t m = mbase + mloc + j * 16 + fr;
      float rs = 0.f, mrs = 0.f;
      if constexpr (MODE == 0) { rs = rstd_a[m]; mrs = murs_a[m]; }
      #pragma unroll
      for (int i = 0; i < 4; ++i) {
        int n = nbase + i * 16 + kg * 4;
        float o0, o1, o2, o3;
        if constexpr (MODE == 0) {
          float4 uu = *(const float4*)(uvec + n);
          float4 vv = *(const float4*)(vvec + n);
          o0 = tanh_fast(rs * acc[i][j][0] - mrs * vv.x + uu.x);
          o1 = tanh_fast(rs * acc[i][j][1] - mrs * vv.y + uu.y);
          o2 = tanh_fast(rs * acc[i][j][2] - mrs * vv.z + uu.z);
          o3 = tanh_fast(rs * acc[i][j][3] - mrs * vv.w + uu.w);
        } else {
          float4 bb = *(const float4*)(bias + n);
          o0 = tanh_fast(acc[i][j][0] + bb.x);
          o1 = tanh_fast(acc[i][j][1] + bb.y);
          o2 = tanh_fast(acc[i][j][2] + bb.z);
          o3 = tanh_fast(acc[i][j][3] + bb.w);
        }
        uint32_t lo = (uint32_t)f2bf(o0) | ((uint32_t)f2bf(o1) << 16);
        uint32_t hi = (uint32_t)f2bf(o2) | ((uint32_t)f2bf(o3) << 16);
        *(uint64_t*)(C + m * 512 + n) = (uint64_t)lo | ((uint64_t)hi << 32);
      }
    }
    __syncthreads();
  }
}

// ---------------------------------------------------------------------------
// value[m] = a2[m,:256] . Wv + bv   (a2 at stride 512; one wave per row)
// ---------------------------------------------------------------------------
__global__ void gemv_kernel(const uint16_t* __restrict__ a2, const float* __restrict__ Wv,
                            const float* __restrict__ bv, float* __restrict__ outv)
{
  const int lane = threadIdx.x & 63;
  const size_t row = (size_t)blockIdx.x * 4 + (threadIdx.x >> 6);
  const uint16_t* p = a2 + row * 512 + lane * 4;
  uint64_t v = *(const uint64_t*)p;
  float4 w = *(const float4*)(Wv + lane * 4);
  float d = bf2f((uint16_t)(v & 0xFFFF)) * w.x
          + bf2f((uint16_t)((v >> 16) & 0xFFFF)) * w.y
          + bf2f((uint16_t)((v >> 32) & 0xFFFF)) * w.z
          + bf2f((uint16_t)((v >> 48) & 0xFFFF)) * w.w;
  #pragma unroll
  for (int o = 1; o < 64; o <<= 1) d += __shfl_xor(d, o);
  if (lane == 0) outv[row] = d + bv[0];
}

// ---------------------------------------------------------------------------
// W1 (fold ln_g into columns) then W2, fp32 -> bf16 contiguous.
// ---------------------------------------------------------------------------
__global__ void wconv_kernel(const float* __restrict__ W1, const float* __restrict__ W2,
                             const float* __restrict__ ln_g, uint16_t* __restrict__ dst)
{
  int idx = blockIdx.x * 256 + threadIdx.x;
  int i4 = idx * 4;
  float4 v;
  if (i4 < 262144) {
    v = *(const float4*)(W1 + i4);
    int c = i4 & 511;
    float4 gv = *(const float4*)(ln_g + c);
    v.x *= gv.x; v.y *= gv.y; v.z *= gv.z; v.w *= gv.w;
  } else {
    v = *(const float4*)(W2 + (i4 - 262144));
  }
  uint32_t lo = (uint32_t)f2bf(v.x) | ((uint32_t)f2bf(v.y) << 16);
  uint32_t hi = (uint32_t)f2bf(v.z) | ((uint32_t)f2bf(v.w) << 16);
  *(uint64_t*)(dst + i4) = (uint64_t)lo | ((uint64_t)hi << 32);
}

extern "C" void kernel_launch(void* const* d_in, const int* in_sizes, int n_in,
                              void* d_out, int out_size, void* d_ws, size_t ws_size,
                              hipStream_t stream)
{
  (void)in_sizes; (void)n_in;
  const float* x    = (const float*)d_in[0];
  const float* done = (const float*)d_in[1];
  const float* h0   = (const float*)d_in[2];
  const float* c0   = (const float*)d_in[3];
  const float* W_ih = (const float*)d_in[4];
  const float* W_hh = (const float*)d_in[5];
  const float* b_ih = (const float*)d_in[6];
  const float* b_hh = (const float*)d_in[7];
  const float* ln_g = (const float*)d_in[8];
  const float* ln_b = (const float*)d_in[9];
  const float* W1   = (const float*)d_in[10];
  const float* b1   = (const float*)d_in[11];
  const float* W2   = (const float*)d_in[12];
  const float* b2   = (const float*)d_in[13];
  const float* Wv   = (const float*)d_in[14];
  const float* bv   = (const float*)d_in[15];
  float* out = (float*)d_out;
  char* ws = (char*)d_ws;

  // ws layout (bytes):
  //   0        flg      4096     (16 groups x 64 per-wave flags, 256B/group)
  //   16384    wbf      786432   (bf16 W1g | W2)
  //   802816   u,v      4096     (512 f32 each)
  //   806912   rstd     524288
  //   1331200  murs     524288
  //   2097152  hs       134217728  (bf16 [T*B,512]; later a1 in-place, a2 cols 0..255)
  constexpr size_t NEED = 2097152ULL + 134217728ULL;
  if (ws_size < NEED) {
    hipMemsetAsync(d_out, 0, (size_t)out_size * 4, stream);
    return;
  }
  uint32_t* flg  = (uint32_t*)ws;
  uint16_t* wbf  = (uint16_t*)(ws + 16384);
  float*    uv_u = (float*)(ws + 802816);
  float*    uv_v = (float*)(ws + 802816 + 2048);
  float*    rstd = (float*)(ws + 806912);
  float*    murs = (float*)(ws + 1331200);
  uint16_t* hsb  = (uint16_t*)(ws + 2097152);

  hipMemsetAsync(ws, 0, 16384, stream);
  hipLaunchKernelGGL(wconv_kernel, dim3(384), dim3(256), 0, stream, W1, W2, ln_g, wbf);
  hipLaunchKernelGGL(uv_kernel, dim3(128), dim3(256), 0, stream, W1, ln_g, ln_b, b1, uv_u, uv_v);
  hipLaunchKernelGGL(lstm_kernel, dim3(256), dim3(256), 0, stream,
                     x, done, h0, c0, W_ih, W_hh, b_ih, b_hh, hsb, flg, out);
  hipLaunchKernelGGL(ln_stats_kernel, dim3(32768), dim3(256), 0, stream, hsb, rstd, murs);
  // GEMM1: a1 = tanh(LN(h) @ W1^T + b1), in-place over hs
  hipLaunchKernelGGL((gemm_fused<0>), dim3(2048), dim3(256), 0, stream,
                     hsb, wbf, hsb, 4, rstd, murs, uv_u, uv_v, (const float*)nullptr);
  // GEMM2: a2 = tanh(a1 @ W2^T + b2), in-place over hs cols [0,256)
  hipLaunchKernelGGL((gemm_fused<1>), dim3(2048), dim3(256), 0, stream,
                     hsb, wbf + 262144, hsb, 2,
                     (const float*)nullptr, (const float*)nullptr,
                     (const float*)nullptr, (const float*)nullptr, b2);
  hipLaunchKernelGGL(gemv_kernel, dim3(32768), dim3(256), 0, stream, hsb, Wv, bv, out);
}

// Round 13
// 1902.834 us; speedup vs baseline: 2.1031x; 1.0325x over previous
//
#include <hip/hip_runtime.h>
#include <stdint.h>

// Problem constants
constexpr int T_STEPS = 512;
constexpr int BSZ     = 256;
constexpr int OBSD    = 64;
constexpr int HID     = 512;
constexpr int NROWS   = T_STEPS * BSZ;   // 131072

// LSTM partitioning: 16 groups x 16 WGs. Group owns 16 batch rows; WG owns
// 32 h-cols (all 4 gates).
constexpr int GROUPS = 16;
constexpr int WPG    = 16;
constexpr int BW     = 16;

typedef __attribute__((ext_vector_type(8))) short bf16x8;
typedef __attribute__((ext_vector_type(4))) float f32x4;

__device__ __forceinline__ float bf2f(uint16_t u) {
  union { uint32_t i; float f; } v; v.i = ((uint32_t)u) << 16; return v.f;
}
__device__ __forceinline__ uint16_t f2bf(float f) {
  union { float f; uint32_t i; } v; v.f = f;
  return (uint16_t)((v.i + 0x7FFFu + ((v.i >> 16) & 1u)) >> 16);
}
__device__ __forceinline__ uint64_t pack4(float a, float b, float c, float d) {
  uint32_t lo = (uint32_t)f2bf(a) | ((uint32_t)f2bf(b) << 16);
  uint32_t hi = (uint32_t)f2bf(c) | ((uint32_t)f2bf(d) << 16);
  return (uint64_t)lo | ((uint64_t)hi << 32);
}
__device__ __forceinline__ float sigm(float x) { return 1.f / (1.f + __expf(-x)); }
__device__ __forceinline__ float tanh_fast(float x) {
  float e = __expf(2.f * x);
  return 1.f - 2.f / (e + 1.f);
}

__device__ __forceinline__ void gll16(const void* g, void* l) {
  __builtin_amdgcn_global_load_lds(
      (const __attribute__((address_space(1))) uint32_t*)g,
      (__attribute__((address_space(3))) uint32_t*)l, 16, 0, 0);
}

// ---------------------------------------------------------------------------
// Persistent LSTM scan. 256 blocks x 256 threads, 1 block/CU.
// == Round-12 kernel (proven 1.53 ms) with one micro-change: flag layout is
// q-major (flg[g*64 + q*16 + win]) so each consumer wave's 16-flag poll is a
// single contiguous 64B read (was 4B x 16 at stride 16B across 256B).
// Transport summary (rounds 5-12): h stores sc1->LIC; h loads plain cacheable
// (safe: write-once per address per dispatch, read only post-flag; start-of-
// kernel agent-acquire drops stale replay lines); flags agent-scope relaxed,
// producer publishes after own vmcnt(0) drain (LIC serializes flag-after-data).
// ---------------------------------------------------------------------------
__global__ __launch_bounds__(256, 1) void lstm_kernel(
    const float* __restrict__ xin, const float* __restrict__ done,
    const float* __restrict__ h0, const float* __restrict__ c0,
    const float* __restrict__ W_ih, const float* __restrict__ W_hh,
    const float* __restrict__ b_ih, const float* __restrict__ b_hh,
    uint16_t* __restrict__ hs, uint32_t* __restrict__ flg,
    float* __restrict__ out)
{
  __shared__ char  Ab[16 * 1152];
  __shared__ float gl[4 * 528];     // [gate][16 rows][33 pad]
  __shared__ float bl[128];         // [gate][32 cols]

  const int wg   = blockIdx.x;
  const int g    = wg & 15;         // group
  const int win  = wg >> 4;         // slot within group -> col block win*32
  const int bg   = g * BW;
  const int tid  = threadIdx.x;
  const int lane = tid & 63;
  const int q    = tid >> 6;        // wave id == gate id

  // one-time: drop stale cache lines from a previous graph replay
  __builtin_amdgcn_fence(__ATOMIC_ACQUIRE, "agent");

  // ---- weights into VGPRs: wave q = gate q, col frags f0=cols 0-15, f1=16-31
  bf16x8 bq0[18], bq1[18];
  {
    const int r0  = q * 512 + win * 32 + (lane & 15);
    const int r1  = r0 + 16;
    const int kg8 = (lane >> 4) * 8;
    #pragma unroll
    for (int ks = 0; ks < 18; ++ks) {
      const float* s0 = (ks < 16)
          ? (W_hh + (size_t)r0 * 512 + ks * 32 + kg8)
          : (W_ih + (size_t)r0 * 64 + (ks - 16) * 32 + kg8);
      const float* s1 = (ks < 16)
          ? (W_hh + (size_t)r1 * 512 + ks * 32 + kg8)
          : (W_ih + (size_t)r1 * 64 + (ks - 16) * 32 + kg8);
      float4 a0 = *(const float4*)s0;
      float4 a1 = *(const float4*)(s0 + 4);
      float4 b0 = *(const float4*)s1;
      float4 b1 = *(const float4*)(s1 + 4);
      bf16x8 va, vb;
      va[0] = (short)f2bf(a0.x); va[1] = (short)f2bf(a0.y);
      va[2] = (short)f2bf(a0.z); va[3] = (short)f2bf(a0.w);
      va[4] = (short)f2bf(a1.x); va[5] = (short)f2bf(a1.y);
      va[6] = (short)f2bf(a1.z); va[7] = (short)f2bf(a1.w);
      vb[0] = (short)f2bf(b0.x); vb[1] = (short)f2bf(b0.y);
      vb[2] = (short)f2bf(b0.z); vb[3] = (short)f2bf(b0.w);
      vb[4] = (short)f2bf(b1.x); vb[5] = (short)f2bf(b1.y);
      vb[6] = (short)f2bf(b1.z); vb[7] = (short)f2bf(b1.w);
      bq0[ks] = va; bq1[ks] = vb;
    }
  }
  if (tid < 128) {
    int gq = tid >> 5, c = tid & 31;
    int grow = gq * 512 + win * 32 + c;
    bl[tid] = b_ih[grow] + b_hh[grow];
  }

  const int b_loc = tid >> 4;        // 0..15 (batch row within group)
  const int n0    = (tid & 15) * 2;  // col pair within WG's 32 cols
  float creg0 = c0[(size_t)(bg + b_loc) * HID + win * 32 + n0];
  float creg1 = c0[(size_t)(bg + b_loc) * HID + win * 32 + n0 + 1];

  const int sr  = tid >> 4;          // x staging row (0..15)
  const int sc4 = (tid & 15) * 4;    // x col base (4 floats/thread)
  const int rw  = q * 4;             // wave's 4 h rows (produce AND consume)

  __syncthreads();

  for (int t = 0; t < T_STEPS; ++t) {
    // ---- hoisted loads (overlap the poll): x_t, done values ----
    const float* xp = xin + ((size_t)t * BSZ + bg + sr) * OBSD + sc4;
    float4 xa = *(const float4*)xp;
    float dvs[4];
    #pragma unroll
    for (int r8 = 0; r8 < 4; ++r8)
      dvs[r8] = done[(size_t)t * BSZ + bg + rw + r8];
    float dv_b = done[(size_t)t * BSZ + bg + b_loc];

    // stage x_t into Ab
    *(uint64_t*)(Ab + ((sr * 1152 + 1024 + sc4 * 2) ^ ((sr & 7) << 4))) =
        pack4(xa.x, xa.y, xa.z, xa.w);

    // ---- wave q waits for its 16 producer-wave-q flags (one 64B read) ----
    if (t > 0) {
      for (;;) {
        uint32_t f = (lane < WPG)
            ? __hip_atomic_load(flg + g * 64 + q * 16 + lane,
                                __ATOMIC_RELAXED, __HIP_MEMORY_SCOPE_AGENT)
            : 0xFFFFFFFFu;
        if (__all((int)(f >= (uint32_t)t))) break;
        __builtin_amdgcn_s_sleep(1);
      }
      __builtin_amdgcn_fence(__ATOMIC_ACQUIRE, "workgroup");
    }

    // ---- stage h_{t-1} rows rw..rw+3 (plain cacheable, 1KB per instr) ----
    if (t == 0) {
      #pragma unroll
      for (int r8 = 0; r8 < 4; ++r8) {
        int r = rw + r8;
        uint64_t v0 = 0, v1 = 0;
        if (dvs[r8] <= 0.5f) {
          const float* hp = h0 + (size_t)(bg + r) * HID;
          float4 ha = *(const float4*)(hp + lane * 4);
          float4 hb = *(const float4*)(hp + 256 + lane * 4);
          v0 = pack4(ha.x, ha.y, ha.z, ha.w);
          v1 = pack4(hb.x, hb.y, hb.z, hb.w);
        }
        *(uint64_t*)(Ab + ((r * 1152 + lane * 8) ^ ((r & 7) << 4))) = v0;
        *(uint64_t*)(Ab + ((r * 1152 + 512 + lane * 8) ^ ((r & 7) << 4))) = v1;
      }
    } else {
      #pragma unroll
      for (int r8 = 0; r8 < 4; ++r8) {
        int r = rw + r8;
        const uint4* hrow =
            (const uint4*)(hs + ((size_t)(t - 1) * BSZ + bg + r) * 512);
        uint4 v = hrow[lane];               // plain load: L1/L2-cacheable
        if (dvs[r8] > 0.5f) { v.x = 0; v.y = 0; v.z = 0; v.w = 0; }
        *(uint4*)(Ab + ((r * 1152 + lane * 16) ^ ((r & 7) << 4))) = v;
      }
    }
    __syncthreads();   // barrier 1: all 16 rows staged

    // ---- MFMA: wave q -> gate q, [16 rows x 32 cols], K=576 ----
    f32x4 ac0 = {0.f, 0.f, 0.f, 0.f};
    f32x4 ac1 = {0.f, 0.f, 0.f, 0.f};
    {
      const int ar = lane & 15;
      const int kg = lane >> 4;
      #pragma unroll
      for (int ks = 0; ks < 18; ++ks) {
        int kb = (ks * 32 + kg * 8) * 2;
        bf16x8 a = *(const bf16x8*)(Ab + ((ar * 1152 + kb) ^ ((ar & 7) << 4)));
        ac0 = __builtin_amdgcn_mfma_f32_16x16x32_bf16(a, bq0[ks], ac0, 0, 0, 0);
        ac1 = __builtin_amdgcn_mfma_f32_16x16x32_bf16(a, bq1[ks], ac1, 0, 0, 0);
      }
    }
    // ---- gates -> LDS exchange (rows padded to 33 words) ----
    {
      int c  = lane & 15;
      int rb = (lane >> 4) * 4;
      #pragma unroll
      for (int r = 0; r < 4; ++r) {
        gl[q * 528 + (rb + r) * 33 + c]      = ac0[r];
        gl[q * 528 + (rb + r) * 33 + 16 + c] = ac1[r];
      }
    }
    __syncthreads();   // barrier 2: all 4 gates exchanged

    // ---- cell update (c lives in registers across all 512 steps) ----
    {
      float m = dv_b > 0.5f ? 0.f : 1.f;
      float h0v, h1v;
      {
        float I = gl[b_loc * 33 + n0]          + bl[n0];
        float F = gl[528 + b_loc * 33 + n0]    + bl[32 + n0];
        float G = gl[1056 + b_loc * 33 + n0]   + bl[64 + n0];
        float O = gl[1584 + b_loc * 33 + n0]   + bl[96 + n0];
        float cc = creg0 * m;
        cc = sigm(F) * cc + sigm(I) * tanh_fast(G);
        creg0 = cc;
        h0v = sigm(O) * tanh_fast(cc);
      }
      {
        int n1 = n0 + 1;
        float I = gl[b_loc * 33 + n1]          + bl[n1];
        float F = gl[528 + b_loc * 33 + n1]    + bl[32 + n1];
        float G = gl[1056 + b_loc * 33 + n1]   + bl[64 + n1];
        float O = gl[1584 + b_loc * 33 + n1]   + bl[96 + n1];
        float cc = creg1 * m;
        cc = sigm(F) * cc + sigm(I) * tanh_fast(G);
        creg1 = cc;
        h1v = sigm(O) * tanh_fast(cc);
      }
      uint32_t pk = (uint32_t)f2bf(h0v) | ((uint32_t)f2bf(h1v) << 16);
      uint32_t* hp = (uint32_t*)(hs + ((size_t)t * BSZ + bg + b_loc) * HID + win * 32 + n0);
      __hip_atomic_store(hp, pk, __ATOMIC_RELAXED, __HIP_MEMORY_SCOPE_AGENT);
      if (t == T_STEPS - 1) {
        size_t ob = (size_t)(bg + b_loc) * HID + win * 32 + n0;
        out[NROWS + ob]         = h0v;
        out[NROWS + ob + 1]     = h1v;
        out[2 * NROWS + ob]     = creg0;
        out[2 * NROWS + ob + 1] = creg1;
      }
    }
    // per-wave flag: own h stores drained at the LIC -> publish immediately
    asm volatile("s_waitcnt vmcnt(0)" ::: "memory");
    if ((tid & 63) == 0)
      __hip_atomic_store(flg + g * 64 + q * 16 + win, (uint32_t)(t + 1),
                         __ATOMIC_RELAXED, __HIP_MEMORY_SCOPE_AGENT);
  }
}

// ---------------------------------------------------------------------------
// u[n] = sum_k ln_b[k]*W1[n,k] + b1[n] ;  v[n] = sum_k ln_g[k]*W1[n,k]
// ---------------------------------------------------------------------------
__global__ void uv_kernel(const float* __restrict__ W1, const float* __restrict__ ln_g,
                          const float* __restrict__ ln_b, const float* __restrict__ b1,
                          float* __restrict__ u, float* __restrict__ v)
{
  const int lane = threadIdx.x & 63;
  const int row  = blockIdx.x * 4 + (threadIdx.x >> 6);
  const float* wp = W1 + (size_t)row * 512 + lane * 8;
  float4 w0 = *(const float4*)wp;
  float4 w1 = *(const float4*)(wp + 4);
  float4 g0 = *(const float4*)(ln_g + lane * 8);
  float4 g1 = *(const float4*)(ln_g + lane * 8 + 4);
  float4 b0 = *(const float4*)(ln_b + lane * 8);
  float4 b1v = *(const float4*)(ln_b + lane * 8 + 4);
  float su = b0.x * w0.x + b0.y * w0.y + b0.z * w0.z + b0.w * w0.w
           + b1v.x * w1.x + b1v.y * w1.y + b1v.z * w1.z + b1v.w * w1.w;
  float sv = g0.x * w0.x + g0.y * w0.y + g0.z * w0.z + g0.w * w0.w
           + g1.x * w1.x + g1.y * w1.y + g1.z * w1.z + g1.w * w1.w;
  #pragma unroll
  for (int o = 1; o < 64; o <<= 1) { su += __shfl_xor(su, o); sv += __shfl_xor(sv, o); }
  if (lane == 0) { u[row] = su + b1[row]; v[row] = sv; }
}

// ---------------------------------------------------------------------------
// Fused GEMM: C = tanh(epilogue(A[64 rows, K=512] @ W[,512]^T))
// MODE 0: LN stats computed IN-BLOCK from the staged A-tile (hidden state):
//         rs/mrs per row -> LDS; epilogue tanh(rs*G - mrs*v_n + u_n).
//         (Replaces the standalone ln_stats kernel: A is already in LDS.)
// MODE 1: bias epilogue  tanh(G + bias_n)
// ---------------------------------------------------------------------------
template<int MODE>
__global__ __launch_bounds__(256, 2) void gemm_fused(
    const uint16_t* __restrict__ Abase, const uint16_t* __restrict__ W,
    uint16_t* __restrict__ C, int ntiles,
    const float* __restrict__ uvec, const float* __restrict__ vvec,
    const float* __restrict__ bias)
{
  __shared__ uint16_t At[64 * 512];   // 65536 B
  __shared__ float sRS[64];
  __shared__ float sMRS[64];
  const int tid  = threadIdx.x;
  const int lane = tid & 63;
  const int wv   = tid >> 6;
  const size_t mbase = (size_t)blockIdx.x * 64;

  for (int r8 = 0; r8 < 16; ++r8) {
    int row = wv * 16 + r8;
    int sb  = (lane * 16) ^ ((row & 7) << 4);
    gll16(Abase + (mbase + row) * 512 + sb / 2, At + row * 512);
  }
  __syncthreads();

  if constexpr (MODE == 0) {
    // per-row LN stats from the staged tile (XOR-swizzle is bijective within
    // a row, so the order-scrambled read still covers each element once)
    for (int r8 = 0; r8 < 16; ++r8) {
      int row = wv * 16 + r8;
      bf16x8 v = *(const bf16x8*)((const char*)At +
                                  ((row * 1024 + lane * 16) ^ ((row & 7) << 4)));
      float s = 0.f, s2 = 0.f;
      #pragma unroll
      for (int j = 0; j < 8; ++j) {
        float f = bf2f((uint16_t)v[j]);
        s += f; s2 += f * f;
      }
      #pragma unroll
      for (int o = 1; o < 64; o <<= 1) {
        s += __shfl_xor(s, o); s2 += __shfl_xor(s2, o);
      }
      if (lane == 0) {
        float mu  = s * (1.f / 512.f);
        float var = s2 * (1.f / 512.f) - mu * mu;
        float rs  = rsqrtf(var + 1e-5f);
        sRS[row]  = rs;
        sMRS[row] = mu * rs;
      }
    }
    __syncthreads();
  }

  const int fr = lane & 15, kg = lane >> 4;
  const int mloc = (wv & 1) * 32;
  const int nhalf = (wv >> 1) * 64;

  for (int nt = 0; nt < ntiles; ++nt) {
    const int nbase = nt * 128 + nhalf;
    f32x4 vz = {0.f, 0.f, 0.f, 0.f};
    f32x4 acc[4][2];
    #pragma unroll
    for (int i = 0; i < 4; ++i) { acc[i][0] = vz; acc[i][1] = vz; }

    #pragma unroll 4
    for (int kb = 0; kb < 16; ++kb) {
      const int ke = kb * 32 + kg * 8;
      bf16x8 wf[4];
      #pragma unroll
      for (int i = 0; i < 4; ++i)
        wf[i] = *(const bf16x8*)(W + (size_t)(nbase + i * 16 + fr) * 512 + ke);
      bf16x8 af[2];
      #pragma unroll
      for (int j = 0; j < 2; ++j) {
        int mr = mloc + j * 16 + fr;
        af[j] = *(const bf16x8*)((const char*)At + ((mr * 1024 + ke * 2) ^ ((mr & 7) << 4)));
      }
      #pragma unroll
      for (int i = 0; i < 4; ++i)
        #pragma unroll
        for (int j = 0; j < 2; ++j)
          acc[i][j] = __builtin_amdgcn_mfma_f32_16x16x32_bf16(wf[i], af[j], acc[i][j], 0, 0, 0);
    }

    #pragma unroll
    for (int j = 0; j < 2; ++j) {
      int ml = mloc + j * 16 + fr;
      size_t m = mbase + ml;
      float rs = 0.f, mrs = 0.f;
      if constexpr (MODE == 0) { rs = sRS[ml]; mrs = sMRS[ml]; }
      #pragma unroll
      for (int i = 0; i < 4; ++i) {
        int n = nbase + i * 16 + kg * 4;
        float o0, o1, o2, o3;
        if constexpr (MODE == 0) {
          float4 uu = *(const float4*)(uvec + n);
          float4 vv = *(const float4*)(vvec + n);
          o0 = tanh_fast(rs * acc[i][j][0] - mrs * vv.x + uu.x);
          o1 = tanh_fast(rs * acc[i][j][1] - mrs * vv.y + uu.y);
          o2 = tanh_fast(rs * acc[i][j][2] - mrs * vv.z + uu.z);
          o3 = tanh_fast(rs * acc[i][j][3] - mrs * vv.w + uu.w);
        } else {
          float4 bb = *(const float4*)(bias + n);
          o0 = tanh_fast(acc[i][j][0] + bb.x);
          o1 = tanh_fast(acc[i][j][1] + bb.y);
          o2 = tanh_fast(acc[i][j][2] + bb.z);
          o3 = tanh_fast(acc[i][j][3] + bb.w);
        }
        uint32_t lo = (uint32_t)f2bf(o0) | ((uint32_t)f2bf(o1) << 16);
        uint32_t hi = (uint32_t)f2bf(o2) | ((uint32_t)f2bf(o3) << 16);
        *(uint64_t*)(C + m * 512 + n) = (uint64_t)lo | ((uint64_t)hi << 32);
      }
    }
    __syncthreads();
  }
}

// ---------------------------------------------------------------------------
// value[m] = a2[m,:256] . Wv + bv   (a2 at stride 512; one wave per row)
// ---------------------------------------------------------------------------
__global__ void gemv_kernel(const uint16_t* __restrict__ a2, const float* __restrict__ Wv,
                            const float* __restrict__ bv, float* __restrict__ outv)
{
  const int lane = threadIdx.x & 63;
  const size_t row = (size_t)blockIdx.x * 4 + (threadIdx.x >> 6);
  const uint16_t* p = a2 + row * 512 + lane * 4;
  uint64_t v = *(const uint64_t*)p;
  float4 w = *(const float4*)(Wv + lane * 4);
  float d = bf2f((uint16_t)(v & 0xFFFF)) * w.x
          + bf2f((uint16_t)((v >> 16) & 0xFFFF)) * w.y
          + bf2f((uint16_t)((v >> 32) & 0xFFFF)) * w.z
          + bf2f((uint16_t)((v >> 48) & 0xFFFF)) * w.w;
  #pragma unroll
  for (int o = 1; o < 64; o <<= 1) d += __shfl_xor(d, o);
  if (lane == 0) outv[row] = d + bv[0];
}

// ---------------------------------------------------------------------------
// W1 (fold ln_g into columns) then W2, fp32 -> bf16 contiguous.
// ---------------------------------------------------------------------------
__global__ void wconv_kernel(const float* __restrict__ W1, const float* __restrict__ W2,
                             const float* __restrict__ ln_g, uint16_t* __restrict__ dst)
{
  int idx = blockIdx.x * 256 + threadIdx.x;
  int i4 = idx * 4;
  float4 v;
  if (i4 < 262144) {
    v = *(const float4*)(W1 + i4);
    int c = i4 & 511;
    float4 gv = *(const float4*)(ln_g + c);
    v.x *= gv.x; v.y *= gv.y; v.z *= gv.z; v.w *= gv.w;
  } else {
    v = *(const float4*)(W2 + (i4 - 262144));
  }
  uint32_t lo = (uint32_t)f2bf(v.x) | ((uint32_t)f2bf(v.y) << 16);
  uint32_t hi = (uint32_t)f2bf(v.z) | ((uint32_t)f2bf(v.w) << 16);
  *(uint64_t*)(dst + i4) = (uint64_t)lo | ((uint64_t)hi << 32);
}

extern "C" void kernel_launch(void* const* d_in, const int* in_sizes, int n_in,
                              void* d_out, int out_size, void* d_ws, size_t ws_size,
                              hipStream_t stream)
{
  (void)in_sizes; (void)n_in;
  const float* x    = (const float*)d_in[0];
  const float* done = (const float*)d_in[1];
  const float* h0   = (const float*)d_in[2];
  const float* c0   = (const float*)d_in[3];
  const float* W_ih = (const float*)d_in[4];
  const float* W_hh = (const float*)d_in[5];
  const float* b_ih = (const float*)d_in[6];
  const float* b_hh = (const float*)d_in[7];
  const float* ln_g = (const float*)d_in[8];
  const float* ln_b = (const float*)d_in[9];
  const float* W1   = (const float*)d_in[10];
  const float* b1   = (const float*)d_in[11];
  const float* W2   = (const float*)d_in[12];
  const float* b2   = (const float*)d_in[13];
  const float* Wv   = (const float*)d_in[14];
  const float* bv   = (const float*)d_in[15];
  float* out = (float*)d_out;
  char* ws = (char*)d_ws;

  // ws layout (bytes):
  //   0        flg      4096     (16 groups x 64 per-wave flags, 256B/group)
  //   16384    wbf      786432   (bf16 W1g | W2)
  //   802816   u,v      4096     (512 f32 each)
  //   2097152  hs       134217728  (bf16 [T*B,512]; later a1 in-place, a2 cols 0..255)
  constexpr size_t NEED = 2097152ULL + 134217728ULL;
  if (ws_size < NEED) {
    hipMemsetAsync(d_out, 0, (size_t)out_size * 4, stream);
    return;
  }
  uint32_t* flg  = (uint32_t*)ws;
  uint16_t* wbf  = (uint16_t*)(ws + 16384);
  float*    uv_u = (float*)(ws + 802816);
  float*    uv_v = (float*)(ws + 802816 + 2048);
  uint16_t* hsb  = (uint16_t*)(ws + 2097152);

  hipMemsetAsync(ws, 0, 16384, stream);
  hipLaunchKernelGGL(wconv_kernel, dim3(384), dim3(256), 0, stream, W1, W2, ln_g, wbf);
  hipLaunchKernelGGL(uv_kernel, dim3(128), dim3(256), 0, stream, W1, ln_g, ln_b, b1, uv_u, uv_v);
  hipLaunchKernelGGL(lstm_kernel, dim3(256), dim3(256), 0, stream,
                     x, done, h0, c0, W_ih, W_hh, b_ih, b_hh, hsb, flg, out);
  // GEMM1: a1 = tanh(LN(h) @ W1^T + b1), LN stats in-block, in-place over hs
  hipLaunchKernelGGL((gemm_fused<0>), dim3(2048), dim3(256), 0, stream,
                     hsb, wbf, hsb, 4, uv_u, uv_v, (const float*)nullptr);
  // GEMM2: a2 = tanh(a1 @ W2^T + b2), in-place over hs cols [0,256)
  hipLaunchKernelGGL((gemm_fused<1>), dim3(2048), dim3(256), 0, stream,
                     hsb, wbf + 262144, hsb, 2,
                     (const float*)nullptr, (const float*)nullptr, b2);
  hipLaunchKernelGGL(gemv_kernel, dim3(32768), dim3(256), 0, stream, hsb, Wv, bv, out);
}

// Round 14
// 1864.567 us; speedup vs baseline: 2.1462x; 1.0205x over previous
//
#include <hip/hip_runtime.h>
#include <stdint.h>

// Problem constants
constexpr int T_STEPS = 512;
constexpr int BSZ     = 256;
constexpr int OBSD    = 64;
constexpr int HID     = 512;
constexpr int NROWS   = T_STEPS * BSZ;   // 131072

// LSTM partitioning: 16 groups x 16 WGs. Group owns 16 batch rows; WG owns
// 32 h-cols (all 4 gates).
constexpr int GROUPS = 16;
constexpr int WPG    = 16;
constexpr int BW     = 16;

typedef __attribute__((ext_vector_type(8))) short bf16x8;
typedef __attribute__((ext_vector_type(4))) float f32x4;

__device__ __forceinline__ float bf2f(uint16_t u) {
  union { uint32_t i; float f; } v; v.i = ((uint32_t)u) << 16; return v.f;
}
__device__ __forceinline__ uint16_t f2bf(float f) {
  union { float f; uint32_t i; } v; v.f = f;
  return (uint16_t)((v.i + 0x7FFFu + ((v.i >> 16) & 1u)) >> 16);
}
__device__ __forceinline__ uint64_t pack4(float a, float b, float c, float d) {
  uint32_t lo = (uint32_t)f2bf(a) | ((uint32_t)f2bf(b) << 16);
  uint32_t hi = (uint32_t)f2bf(c) | ((uint32_t)f2bf(d) << 16);
  return (uint64_t)lo | ((uint64_t)hi << 32);
}
__device__ __forceinline__ float sigm(float x) { return 1.f / (1.f + __expf(-x)); }
__device__ __forceinline__ float tanh_fast(float x) {
  float e = __expf(2.f * x);
  return 1.f - 2.f / (e + 1.f);
}

__device__ __forceinline__ void gll16(const void* g, void* l) {
  __builtin_amdgcn_global_load_lds(
      (const __attribute__((address_space(1))) uint32_t*)g,
      (__attribute__((address_space(3))) uint32_t*)l, 16, 0, 0);
}

// ---------------------------------------------------------------------------
// Persistent LSTM scan. 256 blocks x 256 threads, 1 block/CU.
// == Round-13 kernel (proven 1.48 ms) with sleepless flag polling:
// s_sleep(1) removed from the consumer poll. Round-4's regression was the
// per-poll agent-acquire fences (L2 invalidates), not poll rate; traffic
// check: 1024 waves x 64B / ~700cy RTT ~= 220 GB/s at the LIC -- negligible.
// Transport: h stores sc1->LIC; h loads plain cacheable (write-once per
// address per dispatch, read post-flag; start agent-acquire drops stale
// replay lines); flags agent-scope relaxed, q-major layout (64B poll).
// ---------------------------------------------------------------------------
__global__ __launch_bounds__(256, 1) void lstm_kernel(
    const float* __restrict__ xin, const float* __restrict__ done,
    const float* __restrict__ h0, const float* __restrict__ c0,
    const float* __restrict__ W_ih, const float* __restrict__ W_hh,
    const float* __restrict__ b_ih, const float* __restrict__ b_hh,
    uint16_t* __restrict__ hs, uint32_t* __restrict__ flg,
    float* __restrict__ out)
{
  __shared__ char  Ab[16 * 1152];
  __shared__ float gl[4 * 528];     // [gate][16 rows][33 pad]
  __shared__ float bl[128];         // [gate][32 cols]

  const int wg   = blockIdx.x;
  const int g    = wg & 15;         // group
  const int win  = wg >> 4;         // slot within group -> col block win*32
  const int bg   = g * BW;
  const int tid  = threadIdx.x;
  const int lane = tid & 63;
  const int q    = tid >> 6;        // wave id == gate id

  // one-time: drop stale cache lines from a previous graph replay
  __builtin_amdgcn_fence(__ATOMIC_ACQUIRE, "agent");

  // ---- weights into VGPRs: wave q = gate q, col frags f0=cols 0-15, f1=16-31
  bf16x8 bq0[18], bq1[18];
  {
    const int r0  = q * 512 + win * 32 + (lane & 15);
    const int r1  = r0 + 16;
    const int kg8 = (lane >> 4) * 8;
    #pragma unroll
    for (int ks = 0; ks < 18; ++ks) {
      const float* s0 = (ks < 16)
          ? (W_hh + (size_t)r0 * 512 + ks * 32 + kg8)
          : (W_ih + (size_t)r0 * 64 + (ks - 16) * 32 + kg8);
      const float* s1 = (ks < 16)
          ? (W_hh + (size_t)r1 * 512 + ks * 32 + kg8)
          : (W_ih + (size_t)r1 * 64 + (ks - 16) * 32 + kg8);
      float4 a0 = *(const float4*)s0;
      float4 a1 = *(const float4*)(s0 + 4);
      float4 b0 = *(const float4*)s1;
      float4 b1 = *(const float4*)(s1 + 4);
      bf16x8 va, vb;
      va[0] = (short)f2bf(a0.x); va[1] = (short)f2bf(a0.y);
      va[2] = (short)f2bf(a0.z); va[3] = (short)f2bf(a0.w);
      va[4] = (short)f2bf(a1.x); va[5] = (short)f2bf(a1.y);
      va[6] = (short)f2bf(a1.z); va[7] = (short)f2bf(a1.w);
      vb[0] = (short)f2bf(b0.x); vb[1] = (short)f2bf(b0.y);
      vb[2] = (short)f2bf(b0.z); vb[3] = (short)f2bf(b0.w);
      vb[4] = (short)f2bf(b1.x); vb[5] = (short)f2bf(b1.y);
      vb[6] = (short)f2bf(b1.z); vb[7] = (short)f2bf(b1.w);
      bq0[ks] = va; bq1[ks] = vb;
    }
  }
  if (tid < 128) {
    int gq = tid >> 5, c = tid & 31;
    int grow = gq * 512 + win * 32 + c;
    bl[tid] = b_ih[grow] + b_hh[grow];
  }

  const int b_loc = tid >> 4;        // 0..15 (batch row within group)
  const int n0    = (tid & 15) * 2;  // col pair within WG's 32 cols
  float creg0 = c0[(size_t)(bg + b_loc) * HID + win * 32 + n0];
  float creg1 = c0[(size_t)(bg + b_loc) * HID + win * 32 + n0 + 1];

  const int sr  = tid >> 4;          // x staging row (0..15)
  const int sc4 = (tid & 15) * 4;    // x col base (4 floats/thread)
  const int rw  = q * 4;             // wave's 4 h rows (produce AND consume)

  __syncthreads();

  for (int t = 0; t < T_STEPS; ++t) {
    // ---- hoisted loads (overlap the poll): x_t, done values ----
    const float* xp = xin + ((size_t)t * BSZ + bg + sr) * OBSD + sc4;
    float4 xa = *(const float4*)xp;
    float dvs[4];
    #pragma unroll
    for (int r8 = 0; r8 < 4; ++r8)
      dvs[r8] = done[(size_t)t * BSZ + bg + rw + r8];
    float dv_b = done[(size_t)t * BSZ + bg + b_loc];

    // stage x_t into Ab
    *(uint64_t*)(Ab + ((sr * 1152 + 1024 + sc4 * 2) ^ ((sr & 7) << 4))) =
        pack4(xa.x, xa.y, xa.z, xa.w);

    // ---- wave q waits for its 16 producer-wave-q flags (one 64B read) ----
    if (t > 0) {
      for (;;) {
        uint32_t f = (lane < WPG)
            ? __hip_atomic_load(flg + g * 64 + q * 16 + lane,
                                __ATOMIC_RELAXED, __HIP_MEMORY_SCOPE_AGENT)
            : 0xFFFFFFFFu;
        if (__all((int)(f >= (uint32_t)t))) break;
      }
      __builtin_amdgcn_fence(__ATOMIC_ACQUIRE, "workgroup");
    }

    // ---- stage h_{t-1} rows rw..rw+3 (plain cacheable, 1KB per instr) ----
    if (t == 0) {
      #pragma unroll
      for (int r8 = 0; r8 < 4; ++r8) {
        int r = rw + r8;
        uint64_t v0 = 0, v1 = 0;
        if (dvs[r8] <= 0.5f) {
          const float* hp = h0 + (size_t)(bg + r) * HID;
          float4 ha = *(const float4*)(hp + lane * 4);
          float4 hb = *(const float4*)(hp + 256 + lane * 4);
          v0 = pack4(ha.x, ha.y, ha.z, ha.w);
          v1 = pack4(hb.x, hb.y, hb.z, hb.w);
        }
        *(uint64_t*)(Ab + ((r * 1152 + lane * 8) ^ ((r & 7) << 4))) = v0;
        *(uint64_t*)(Ab + ((r * 1152 + 512 + lane * 8) ^ ((r & 7) << 4))) = v1;
      }
    } else {
      #pragma unroll
      for (int r8 = 0; r8 < 4; ++r8) {
        int r = rw + r8;
        const uint4* hrow =
            (const uint4*)(hs + ((size_t)(t - 1) * BSZ + bg + r) * 512);
        uint4 v = hrow[lane];               // plain load: L1/L2-cacheable
        if (dvs[r8] > 0.5f) { v.x = 0; v.y = 0; v.z = 0; v.w = 0; }
        *(uint4*)(Ab + ((r * 1152 + lane * 16) ^ ((r & 7) << 4))) = v;
      }
    }
    __syncthreads();   // barrier 1: all 16 rows staged

    // ---- MFMA: wave q -> gate q, [16 rows x 32 cols], K=576 ----
    f32x4 ac0 = {0.f, 0.f, 0.f, 0.f};
    f32x4 ac1 = {0.f, 0.f, 0.f, 0.f};
    {
      const int ar = lane & 15;
      const int kg = lane >> 4;
      #pragma unroll
      for (int ks = 0; ks < 18; ++ks) {
        int kb = (ks * 32 + kg * 8) * 2;
        bf16x8 a = *(const bf16x8*)(Ab + ((ar * 1152 + kb) ^ ((ar & 7) << 4)));
        ac0 = __builtin_amdgcn_mfma_f32_16x16x32_bf16(a, bq0[ks], ac0, 0, 0, 0);
        ac1 = __builtin_amdgcn_mfma_f32_16x16x32_bf16(a, bq1[ks], ac1, 0, 0, 0);
      }
    }
    // ---- gates -> LDS exchange (rows padded to 33 words) ----
    {
      int c  = lane & 15;
      int rb = (lane >> 4) * 4;
      #pragma unroll
      for (int r = 0; r < 4; ++r) {
        gl[q * 528 + (rb + r) * 33 + c]      = ac0[r];
        gl[q * 528 + (rb + r) * 33 + 16 + c] = ac1[r];
      }
    }
    __syncthreads();   // barrier 2: all 4 gates exchanged

    // ---- cell update (c lives in registers across all 512 steps) ----
    {
      float m = dv_b > 0.5f ? 0.f : 1.f;
      float h0v, h1v;
      {
        float I = gl[b_loc * 33 + n0]          + bl[n0];
        float F = gl[528 + b_loc * 33 + n0]    + bl[32 + n0];
        float G = gl[1056 + b_loc * 33 + n0]   + bl[64 + n0];
        float O = gl[1584 + b_loc * 33 + n0]   + bl[96 + n0];
        float cc = creg0 * m;
        cc = sigm(F) * cc + sigm(I) * tanh_fast(G);
        creg0 = cc;
        h0v = sigm(O) * tanh_fast(cc);
      }
      {
        int n1 = n0 + 1;
        float I = gl[b_loc * 33 + n1]          + bl[n1];
        float F = gl[528 + b_loc * 33 + n1]    + bl[32 + n1];
        float G = gl[1056 + b_loc * 33 + n1]   + bl[64 + n1];
        float O = gl[1584 + b_loc * 33 + n1]   + bl[96 + n1];
        float cc = creg1 * m;
        cc = sigm(F) * cc + sigm(I) * tanh_fast(G);
        creg1 = cc;
        h1v = sigm(O) * tanh_fast(cc);
      }
      uint32_t pk = (uint32_t)f2bf(h0v) | ((uint32_t)f2bf(h1v) << 16);
      uint32_t* hp = (uint32_t*)(hs + ((size_t)t * BSZ + bg + b_loc) * HID + win * 32 + n0);
      __hip_atomic_store(hp, pk, __ATOMIC_RELAXED, __HIP_MEMORY_SCOPE_AGENT);
      if (t == T_STEPS - 1) {
        size_t ob = (size_t)(bg + b_loc) * HID + win * 32 + n0;
        out[NROWS + ob]         = h0v;
        out[NROWS + ob + 1]     = h1v;
        out[2 * NROWS + ob]     = creg0;
        out[2 * NROWS + ob + 1] = creg1;
      }
    }
    // per-wave flag: own h stores drained at the LIC -> publish immediately
    asm volatile("s_waitcnt vmcnt(0)" ::: "memory");
    if ((tid & 63) == 0)
      __hip_atomic_store(flg + g * 64 + q * 16 + win, (uint32_t)(t + 1),
                         __ATOMIC_RELAXED, __HIP_MEMORY_SCOPE_AGENT);
  }
}

// ---------------------------------------------------------------------------
// Prep (merged): blocks 0..383 convert W1*ln_g | W2 fp32->bf16;
// blocks 384..511 compute u[n], v[n] (one wave per W1 row).
// ---------------------------------------------------------------------------
__global__ void prep_kernel(const float* __restrict__ W1, const float* __restrict__ W2,
                            const float* __restrict__ ln_g, const float* __restrict__ ln_b,
                            const float* __restrict__ b1, uint16_t* __restrict__ dst,
                            float* __restrict__ u, float* __restrict__ v)
{
  if (blockIdx.x < 384) {
    int idx = blockIdx.x * 256 + threadIdx.x;
    int i4 = idx * 4;
    float4 val;
    if (i4 < 262144) {
      val = *(const float4*)(W1 + i4);
      int c = i4 & 511;
      float4 gv = *(const float4*)(ln_g + c);
      val.x *= gv.x; val.y *= gv.y; val.z *= gv.z; val.w *= gv.w;
    } else {
      val = *(const float4*)(W2 + (i4 - 262144));
    }
    uint32_t lo = (uint32_t)f2bf(val.x) | ((uint32_t)f2bf(val.y) << 16);
    uint32_t hi = (uint32_t)f2bf(val.z) | ((uint32_t)f2bf(val.w) << 16);
    *(uint64_t*)(dst + i4) = (uint64_t)lo | ((uint64_t)hi << 32);
  } else {
    const int lane = threadIdx.x & 63;
    const int row  = (blockIdx.x - 384) * 4 + (threadIdx.x >> 6);
    const float* wp = W1 + (size_t)row * 512 + lane * 8;
    float4 w0 = *(const float4*)wp;
    float4 w1 = *(const float4*)(wp + 4);
    float4 g0 = *(const float4*)(ln_g + lane * 8);
    float4 g1 = *(const float4*)(ln_g + lane * 8 + 4);
    float4 b0 = *(const float4*)(ln_b + lane * 8);
    float4 b1v = *(const float4*)(ln_b + lane * 8 + 4);
    float su = b0.x * w0.x + b0.y * w0.y + b0.z * w0.z + b0.w * w0.w
             + b1v.x * w1.x + b1v.y * w1.y + b1v.z * w1.z + b1v.w * w1.w;
    float sv = g0.x * w0.x + g0.y * w0.y + g0.z * w0.z + g0.w * w0.w
             + g1.x * w1.x + g1.y * w1.y + g1.z * w1.z + g1.w * w1.w;
    #pragma unroll
    for (int o = 1; o < 64; o <<= 1) { su += __shfl_xor(su, o); sv += __shfl_xor(sv, o); }
    if (lane == 0) { u[row] = su + b1[row]; v[row] = sv; }
  }
}

// ---------------------------------------------------------------------------
// GEMM1: a1 = tanh(LN(h) @ W1g^T + ...), LN stats in-block, in-place over hs.
// ---------------------------------------------------------------------------
__global__ __launch_bounds__(256, 2) void gemm1_kernel(
    const uint16_t* __restrict__ Abase, const uint16_t* __restrict__ W,
    uint16_t* __restrict__ C,
    const float* __restrict__ uvec, const float* __restrict__ vvec)
{
  __shared__ uint16_t At[64 * 512];   // 65536 B
  __shared__ float sRS[64];
  __shared__ float sMRS[64];
  const int tid  = threadIdx.x;
  const int lane = tid & 63;
  const int wv   = tid >> 6;
  const size_t mbase = (size_t)blockIdx.x * 64;

  for (int r8 = 0; r8 < 16; ++r8) {
    int row = wv * 16 + r8;
    int sb  = (lane * 16) ^ ((row & 7) << 4);
    gll16(Abase + (mbase + row) * 512 + sb / 2, At + row * 512);
  }
  __syncthreads();

  // per-row LN stats from the staged tile (swizzle is bijective per row)
  for (int r8 = 0; r8 < 16; ++r8) {
    int row = wv * 16 + r8;
    bf16x8 v = *(const bf16x8*)((const char*)At +
                                ((row * 1024 + lane * 16) ^ ((row & 7) << 4)));
    float s = 0.f, s2 = 0.f;
    #pragma unroll
    for (int j = 0; j < 8; ++j) {
      float f = bf2f((uint16_t)v[j]);
      s += f; s2 += f * f;
    }
    #pragma unroll
    for (int o = 1; o < 64; o <<= 1) {
      s += __shfl_xor(s, o); s2 += __shfl_xor(s2, o);
    }
    if (lane == 0) {
      float mu  = s * (1.f / 512.f);
      float var = s2 * (1.f / 512.f) - mu * mu;
      float rs  = rsqrtf(var + 1e-5f);
      sRS[row]  = rs;
      sMRS[row] = mu * rs;
    }
  }
  __syncthreads();

  const int fr = lane & 15, kg = lane >> 4;
  const int mloc = (wv & 1) * 32;
  const int nhalf = (wv >> 1) * 64;

  for (int nt = 0; nt < 4; ++nt) {
    const int nbase = nt * 128 + nhalf;
    f32x4 vz = {0.f, 0.f, 0.f, 0.f};
    f32x4 acc[4][2];
    #pragma unroll
    for (int i = 0; i < 4; ++i) { acc[i][0] = vz; acc[i][1] = vz; }

    #pragma unroll 4
    for (int kb = 0; kb < 16; ++kb) {
      const int ke = kb * 32 + kg * 8;
      bf16x8 wf[4];
      #pragma unroll
      for (int i = 0; i < 4; ++i)
        wf[i] = *(const bf16x8*)(W + (size_t)(nbase + i * 16 + fr) * 512 + ke);
      bf16x8 af[2];
      #pragma unroll
      for (int j = 0; j < 2; ++j) {
        int mr = mloc + j * 16 + fr;
        af[j] = *(const bf16x8*)((const char*)At + ((mr * 1024 + ke * 2) ^ ((mr & 7) << 4)));
      }
      #pragma unroll
      for (int i = 0; i < 4; ++i)
        #pragma unroll
        for (int j = 0; j < 2; ++j)
          acc[i][j] = __builtin_amdgcn_mfma_f32_16x16x32_bf16(wf[i], af[j], acc[i][j], 0, 0, 0);
    }

    #pragma unroll
    for (int j = 0; j < 2; ++j) {
      int ml = mloc + j * 16 + fr;
      size_t m = mbase + ml;
      float rs = sRS[ml], mrs = sMRS[ml];
      #pragma unroll
      for (int i = 0; i < 4; ++i) {
        int n = nbase + i * 16 + kg * 4;
        float4 uu = *(const float4*)(uvec + n);
        float4 vv = *(const float4*)(vvec + n);
        float o0 = tanh_fast(rs * acc[i][j][0] - mrs * vv.x + uu.x);
        float o1 = tanh_fast(rs * acc[i][j][1] - mrs * vv.y + uu.y);
        float o2 = tanh_fast(rs * acc[i][j][2] - mrs * vv.z + uu.z);
        float o3 = tanh_fast(rs * acc[i][j][3] - mrs * vv.w + uu.w);
        uint32_t lo = (uint32_t)f2bf(o0) | ((uint32_t)f2bf(o1) << 16);
        uint32_t hi = (uint32_t)f2bf(o2) | ((uint32_t)f2bf(o3) << 16);
        *(uint64_t*)(C + m * 512 + n) = (uint64_t)lo | ((uint64_t)hi << 32);
      }
    }
    __syncthreads();  // C overwrites A's source region; keep waves together
  }
}

// ---------------------------------------------------------------------------
// GEMM2+GEMV fused: value[m] = sum_n tanh(a1[m,:]@W2[n,:]^T + b2[n])*Wv[n]+bv
// a2 never materialized. Block: 64 rows x all 256 n-cols (nt=0,1).
// Row m's partials: waves (wv,wv+2) x 4 kg-lanes -> shfl_xor(16,32) + LDS.
// ---------------------------------------------------------------------------
__global__ __launch_bounds__(256, 2) void gemm2_value_kernel(
    const uint16_t* __restrict__ Abase, const uint16_t* __restrict__ W,
    const float* __restrict__ bias, const float* __restrict__ Wv,
    const float* __restrict__ bv, float* __restrict__ outv)
{
  __shared__ uint16_t At[64 * 512];   // 65536 B
  __shared__ float vred[2][64];
  const int tid  = threadIdx.x;
  const int lane = tid & 63;
  const int wv   = tid >> 6;
  const size_t mbase = (size_t)blockIdx.x * 64;

  for (int r8 = 0; r8 < 16; ++r8) {
    int row = wv * 16 + r8;
    int sb  = (lane * 16) ^ ((row & 7) << 4);
    gll16(Abase + (mbase + row) * 512 + sb / 2, At + row * 512);
  }
  __syncthreads();

  const int fr = lane & 15, kg = lane >> 4;
  const int mloc = (wv & 1) * 32;
  const int nhalf = (wv >> 1) * 64;

  float vpart0 = 0.f, vpart1 = 0.f;

  #pragma unroll
  for (int nt = 0; nt < 2; ++nt) {
    const int nbase = nt * 128 + nhalf;
    f32x4 vz = {0.f, 0.f, 0.f, 0.f};
    f32x4 acc[4][2];
    #pragma unroll
    for (int i = 0; i < 4; ++i) { acc[i][0] = vz; acc[i][1] = vz; }

    #pragma unroll 4
    for (int kb = 0; kb < 16; ++kb) {
      const int ke = kb * 32 + kg * 8;
      bf16x8 wf[4];
      #pragma unroll
      for (int i = 0; i < 4; ++i)
        wf[i] = *(const bf16x8*)(W + (size_t)(nbase + i * 16 + fr) * 512 + ke);
      bf16x8 af[2];
      #pragma unroll
      for (int j = 0; j < 2; ++j) {
        int mr = mloc + j * 16 + fr;
        af[j] = *(const bf16x8*)((const char*)At + ((mr * 1024 + ke * 2) ^ ((mr & 7) << 4)));
      }
      #pragma unroll
      for (int i = 0; i < 4; ++i)
        #pragma unroll
        for (int j = 0; j < 2; ++j)
          acc[i][j] = __builtin_amdgcn_mfma_f32_16x16x32_bf16(wf[i], af[j], acc[i][j], 0, 0, 0);
    }

    #pragma unroll
    for (int j = 0; j < 2; ++j) {
      float vp = 0.f;
      #pragma unroll
      for (int i = 0; i < 4; ++i) {
        int n = nbase + i * 16 + kg * 4;
        float4 bb  = *(const float4*)(bias + n);
        float4 wv4 = *(const float4*)(Wv + n);
        vp += tanh_fast(acc[i][j][0] + bb.x) * wv4.x
            + tanh_fast(acc[i][j][1] + bb.y) * wv4.y
            + tanh_fast(acc[i][j][2] + bb.z) * wv4.z
            + tanh_fast(acc[i][j][3] + bb.w) * wv4.w;
      }
      if (j == 0) vpart0 += vp; else vpart1 += vp;
    }
  }

  // reduce across kg lanes (fr fixed): lanes fr, fr+16, fr+32, fr+48
  vpart0 += __shfl_xor(vpart0, 16); vpart0 += __shfl_xor(vpart0, 32);
  vpart1 += __shfl_xor(vpart1, 16); vpart1 += __shfl_xor(vpart1, 32);
  if (kg == 0) {
    vred[wv >> 1][mloc + fr]      = vpart0;
    vred[wv >> 1][mloc + 16 + fr] = vpart1;
  }
  __syncthreads();
  if (tid < 64)
    outv[mbase + tid] = vred[0][tid] + vred[1][tid] + bv[0];
}

extern "C" void kernel_launch(void* const* d_in, const int* in_sizes, int n_in,
                              void* d_out, int out_size, void* d_ws, size_t ws_size,
                              hipStream_t stream)
{
  (void)in_sizes; (void)n_in;
  const float* x    = (const float*)d_in[0];
  const float* done = (const float*)d_in[1];
  const float* h0   = (const float*)d_in[2];
  const float* c0   = (const float*)d_in[3];
  const float* W_ih = (const float*)d_in[4];
  const float* W_hh = (const float*)d_in[5];
  const float* b_ih = (const float*)d_in[6];
  const float* b_hh = (const float*)d_in[7];
  const float* ln_g = (const float*)d_in[8];
  const float* ln_b = (const float*)d_in[9];
  const float* W1   = (const float*)d_in[10];
  const float* b1   = (const float*)d_in[11];
  const float* W2   = (const float*)d_in[12];
  const float* b2   = (const float*)d_in[13];
  const float* Wv   = (const float*)d_in[14];
  const float* bv   = (const float*)d_in[15];
  float* out = (float*)d_out;
  char* ws = (char*)d_ws;

  // ws layout (bytes):
  //   0        flg      4096     (16 groups x 64 per-wave flags, q-major)
  //   16384    wbf      786432   (bf16 W1g | W2)
  //   802816   u,v      4096     (512 f32 each)
  //   2097152  hs       134217728  (bf16 [T*B,512]; a1 in-place after gemm1)
  constexpr size_t NEED = 2097152ULL + 134217728ULL;
  if (ws_size < NEED) {
    hipMemsetAsync(d_out, 0, (size_t)out_size * 4, stream);
    return;
  }
  uint32_t* flg  = (uint32_t*)ws;
  uint16_t* wbf  = (uint16_t*)(ws + 16384);
  float*    uv_u = (float*)(ws + 802816);
  float*    uv_v = (float*)(ws + 802816 + 2048);
  uint16_t* hsb  = (uint16_t*)(ws + 2097152);

  hipMemsetAsync(ws, 0, 16384, stream);
  hipLaunchKernelGGL(prep_kernel, dim3(512), dim3(256), 0, stream,
                     W1, W2, ln_g, ln_b, b1, wbf, uv_u, uv_v);
  hipLaunchKernelGGL(lstm_kernel, dim3(256), dim3(256), 0, stream,
                     x, done, h0, c0, W_ih, W_hh, b_ih, b_hh, hsb, flg, out);
  // GEMM1: a1 = tanh(LN(h) @ W1g^T + ...), LN stats in-block, in-place over hs
  hipLaunchKernelGGL(gemm1_kernel, dim3(2048), dim3(256), 0, stream,
                     hsb, wbf, hsb, uv_u, uv_v);
  // GEMM2+GEMV fused: value directly, a2 never materialized
  hipLaunchKernelGGL(gemm2_value_kernel, dim3(2048), dim3(256), 0, stream,
                     hsb, wbf + 262144, b2, Wv, bv, out);
}

// Round 15
// 1844.093 us; speedup vs baseline: 2.1701x; 1.0111x over previous
//
#include <hip/hip_runtime.h>
#include <stdint.h>

// Problem constants
constexpr int T_STEPS = 512;
constexpr int BSZ     = 256;
constexpr int OBSD    = 64;
constexpr int HID     = 512;
constexpr int NROWS   = T_STEPS * BSZ;   // 131072

// LSTM partitioning: 16 groups x 16 WGs. Group owns 16 batch rows; WG owns
// 32 h-cols (all 4 gates).
constexpr int GROUPS = 16;
constexpr int WPG    = 16;
constexpr int BW     = 16;

typedef __attribute__((ext_vector_type(8))) short bf16x8;
typedef __attribute__((ext_vector_type(4))) float f32x4;

__device__ __forceinline__ float bf2f(uint16_t u) {
  union { uint32_t i; float f; } v; v.i = ((uint32_t)u) << 16; return v.f;
}
__device__ __forceinline__ uint16_t f2bf(float f) {
  union { float f; uint32_t i; } v; v.f = f;
  return (uint16_t)((v.i + 0x7FFFu + ((v.i >> 16) & 1u)) >> 16);
}
__device__ __forceinline__ uint64_t pack4(float a, float b, float c, float d) {
  uint32_t lo = (uint32_t)f2bf(a) | ((uint32_t)f2bf(b) << 16);
  uint32_t hi = (uint32_t)f2bf(c) | ((uint32_t)f2bf(d) << 16);
  return (uint64_t)lo | ((uint64_t)hi << 32);
}
__device__ __forceinline__ float sigm(float x) { return 1.f / (1.f + __expf(-x)); }
__device__ __forceinline__ float tanh_fast(float x) {
  float e = __expf(2.f * x);
  return 1.f - 2.f / (e + 1.f);
}

__device__ __forceinline__ void gll16(const void* g, void* l) {
  __builtin_amdgcn_global_load_lds(
      (const __attribute__((address_space(1))) uint32_t*)g,
      (__attribute__((address_space(3))) uint32_t*)l, 16, 0, 0);
}

// ---------------------------------------------------------------------------
// Persistent LSTM scan. 256 blocks x 256 threads, 1 block/CU.
// == Round-14 kernel (proven 1.47 ms) with the x-contribution moved OFF the
// critical path: each lane loads its own W_ih A-fragments of x_t from global
// (L1/L2-hot) into registers and the 2 x-MFMAs issue BEFORE the flag poll --
// their latency hides under detection. Post-barrier MFMA phase is 16 ks (h
// only); x never touches LDS (barrier 1 gates only the h staging).
// Transport: h stores sc1->LIC; h loads plain cacheable (write-once per
// address per dispatch, read post-flag; start agent-acquire drops stale
// replay lines); flags agent-scope relaxed, q-major (single 64B poll read).
// ---------------------------------------------------------------------------
__global__ __launch_bounds__(256, 1) void lstm_kernel(
    const float* __restrict__ xin, const float* __restrict__ done,
    const float* __restrict__ h0, const float* __restrict__ c0,
    const float* __restrict__ W_ih, const float* __restrict__ W_hh,
    const float* __restrict__ b_ih, const float* __restrict__ b_hh,
    uint16_t* __restrict__ hs, uint32_t* __restrict__ flg,
    float* __restrict__ out)
{
  __shared__ char  Ab[16 * 1152];   // h rows only (first 1024B of each row)
  __shared__ float gl[4 * 528];     // [gate][16 rows][33 pad]
  __shared__ float bl[128];         // [gate][32 cols]

  const int wg   = blockIdx.x;
  const int g    = wg & 15;         // group
  const int win  = wg >> 4;         // slot within group -> col block win*32
  const int bg   = g * BW;
  const int tid  = threadIdx.x;
  const int lane = tid & 63;
  const int q    = tid >> 6;        // wave id == gate id

  // one-time: drop stale cache lines from a previous graph replay
  __builtin_amdgcn_fence(__ATOMIC_ACQUIRE, "agent");

  // ---- weights into VGPRs: wave q = gate q, col frags f0=cols 0-15, f1=16-31
  bf16x8 bq0[18], bq1[18];
  {
    const int r0  = q * 512 + win * 32 + (lane & 15);
    const int r1  = r0 + 16;
    const int kg8 = (lane >> 4) * 8;
    #pragma unroll
    for (int ks = 0; ks < 18; ++ks) {
      const float* s0 = (ks < 16)
          ? (W_hh + (size_t)r0 * 512 + ks * 32 + kg8)
          : (W_ih + (size_t)r0 * 64 + (ks - 16) * 32 + kg8);
      const float* s1 = (ks < 16)
          ? (W_hh + (size_t)r1 * 512 + ks * 32 + kg8)
          : (W_ih + (size_t)r1 * 64 + (ks - 16) * 32 + kg8);
      float4 a0 = *(const float4*)s0;
      float4 a1 = *(const float4*)(s0 + 4);
      float4 b0 = *(const float4*)s1;
      float4 b1 = *(const float4*)(s1 + 4);
      bf16x8 va, vb;
      va[0] = (short)f2bf(a0.x); va[1] = (short)f2bf(a0.y);
      va[2] = (short)f2bf(a0.z); va[3] = (short)f2bf(a0.w);
      va[4] = (short)f2bf(a1.x); va[5] = (short)f2bf(a1.y);
      va[6] = (short)f2bf(a1.z); va[7] = (short)f2bf(a1.w);
      vb[0] = (short)f2bf(b0.x); vb[1] = (short)f2bf(b0.y);
      vb[2] = (short)f2bf(b0.z); vb[3] = (short)f2bf(b0.w);
      vb[4] = (short)f2bf(b1.x); vb[5] = (short)f2bf(b1.y);
      vb[6] = (short)f2bf(b1.z); vb[7] = (short)f2bf(b1.w);
      bq0[ks] = va; bq1[ks] = vb;
    }
  }
  if (tid < 128) {
    int gq = tid >> 5, c = tid & 31;
    int grow = gq * 512 + win * 32 + c;
    bl[tid] = b_ih[grow] + b_hh[grow];
  }

  const int b_loc = tid >> 4;        // 0..15 (batch row within group)
  const int n0    = (tid & 15) * 2;  // col pair within WG's 32 cols
  float creg0 = c0[(size_t)(bg + b_loc) * HID + win * 32 + n0];
  float creg1 = c0[(size_t)(bg + b_loc) * HID + win * 32 + n0 + 1];

  const int ar  = lane & 15;         // MFMA A row for this lane
  const int kg  = lane >> 4;         // MFMA k-group
  const int rw  = q * 4;             // wave's 4 h rows (produce AND consume)

  __syncthreads();

  for (int t = 0; t < T_STEPS; ++t) {
    // ---- hoisted loads (overlap the poll): done values, x A-fragments ----
    float dvs[4];
    #pragma unroll
    for (int r8 = 0; r8 < 4; ++r8)
      dvs[r8] = done[(size_t)t * BSZ + bg + rw + r8];
    float dv_b = done[(size_t)t * BSZ + bg + b_loc];

    // per-lane x A-fragments (row ar, k-groups for ks=16,17) from global
    const float* xrow = xin + ((size_t)t * BSZ + bg + ar) * OBSD + kg * 8;
    float4 x0a = *(const float4*)(xrow);
    float4 x0b = *(const float4*)(xrow + 4);
    float4 x1a = *(const float4*)(xrow + 32);
    float4 x1b = *(const float4*)(xrow + 36);
    bf16x8 xk0, xk1;
    xk0[0] = (short)f2bf(x0a.x); xk0[1] = (short)f2bf(x0a.y);
    xk0[2] = (short)f2bf(x0a.z); xk0[3] = (short)f2bf(x0a.w);
    xk0[4] = (short)f2bf(x0b.x); xk0[5] = (short)f2bf(x0b.y);
    xk0[6] = (short)f2bf(x0b.z); xk0[7] = (short)f2bf(x0b.w);
    xk1[0] = (short)f2bf(x1a.x); xk1[1] = (short)f2bf(x1a.y);
    xk1[2] = (short)f2bf(x1a.z); xk1[3] = (short)f2bf(x1a.w);
    xk1[4] = (short)f2bf(x1b.x); xk1[5] = (short)f2bf(x1b.y);
    xk1[6] = (short)f2bf(x1b.z); xk1[7] = (short)f2bf(x1b.w);

    // ---- x-MFMA issued BEFORE the poll (independent of h) ----
    f32x4 ac0 = {0.f, 0.f, 0.f, 0.f};
    f32x4 ac1 = {0.f, 0.f, 0.f, 0.f};
    ac0 = __builtin_amdgcn_mfma_f32_16x16x32_bf16(xk0, bq0[16], ac0, 0, 0, 0);
    ac1 = __builtin_amdgcn_mfma_f32_16x16x32_bf16(xk0, bq1[16], ac1, 0, 0, 0);
    ac0 = __builtin_amdgcn_mfma_f32_16x16x32_bf16(xk1, bq0[17], ac0, 0, 0, 0);
    ac1 = __builtin_amdgcn_mfma_f32_16x16x32_bf16(xk1, bq1[17], ac1, 0, 0, 0);

    // ---- wave q waits for its 16 producer-wave-q flags (one 64B read) ----
    if (t > 0) {
      for (;;) {
        uint32_t f = (lane < WPG)
            ? __hip_atomic_load(flg + g * 64 + q * 16 + lane,
                                __ATOMIC_RELAXED, __HIP_MEMORY_SCOPE_AGENT)
            : 0xFFFFFFFFu;
        if (__all((int)(f >= (uint32_t)t))) break;
      }
      __builtin_amdgcn_fence(__ATOMIC_ACQUIRE, "workgroup");
    }

    // ---- stage h_{t-1} rows rw..rw+3 (plain cacheable, 1KB per instr) ----
    if (t == 0) {
      #pragma unroll
      for (int r8 = 0; r8 < 4; ++r8) {
        int r = rw + r8;
        uint64_t v0 = 0, v1 = 0;
        if (dvs[r8] <= 0.5f) {
          const float* hp = h0 + (size_t)(bg + r) * HID;
          float4 ha = *(const float4*)(hp + lane * 4);
          float4 hb = *(const float4*)(hp + 256 + lane * 4);
          v0 = pack4(ha.x, ha.y, ha.z, ha.w);
          v1 = pack4(hb.x, hb.y, hb.z, hb.w);
        }
        *(uint64_t*)(Ab + ((r * 1152 + lane * 8) ^ ((r & 7) << 4))) = v0;
        *(uint64_t*)(Ab + ((r * 1152 + 512 + lane * 8) ^ ((r & 7) << 4))) = v1;
      }
    } else {
      #pragma unroll
      for (int r8 = 0; r8 < 4; ++r8) {
        int r = rw + r8;
        const uint4* hrow =
            (const uint4*)(hs + ((size_t)(t - 1) * BSZ + bg + r) * 512);
        uint4 v = hrow[lane];               // plain load: L1/L2-cacheable
        if (dvs[r8] > 0.5f) { v.x = 0; v.y = 0; v.z = 0; v.w = 0; }
        *(uint4*)(Ab + ((r * 1152 + lane * 16) ^ ((r & 7) << 4))) = v;
      }
    }
    __syncthreads();   // barrier 1: all 16 h rows staged

    // ---- MFMA: wave q -> gate q, [16 rows x 32 cols], h part K=512 ----
    #pragma unroll
    for (int ks = 0; ks < 16; ++ks) {
      int kb = ks * 64 + kg * 16;
      bf16x8 a = *(const bf16x8*)(Ab + ((ar * 1152 + kb) ^ ((ar & 7) << 4)));
      ac0 = __builtin_amdgcn_mfma_f32_16x16x32_bf16(a, bq0[ks], ac0, 0, 0, 0);
      ac1 = __builtin_amdgcn_mfma_f32_16x16x32_bf16(a, bq1[ks], ac1, 0, 0, 0);
    }
    // ---- gates -> LDS exchange (rows padded to 33 words) ----
    {
      int c  = lane & 15;
      int rb = (lane >> 4) * 4;
      #pragma unroll
      for (int r = 0; r < 4; ++r) {
        gl[q * 528 + (rb + r) * 33 + c]      = ac0[r];
        gl[q * 528 + (rb + r) * 33 + 16 + c] = ac1[r];
      }
    }
    __syncthreads();   // barrier 2: all 4 gates exchanged

    // ---- cell update (c lives in registers across all 512 steps) ----
    {
      float m = dv_b > 0.5f ? 0.f : 1.f;
      float h0v, h1v;
      {
        float I = gl[b_loc * 33 + n0]          + bl[n0];
        float F = gl[528 + b_loc * 33 + n0]    + bl[32 + n0];
        float G = gl[1056 + b_loc * 33 + n0]   + bl[64 + n0];
        float O = gl[1584 + b_loc * 33 + n0]   + bl[96 + n0];
        float cc = creg0 * m;
        cc = sigm(F) * cc + sigm(I) * tanh_fast(G);
        creg0 = cc;
        h0v = sigm(O) * tanh_fast(cc);
      }
      {
        int n1 = n0 + 1;
        float I = gl[b_loc * 33 + n1]          + bl[n1];
        float F = gl[528 + b_loc * 33 + n1]    + bl[32 + n1];
        float G = gl[1056 + b_loc * 33 + n1]   + bl[64 + n1];
        float O = gl[1584 + b_loc * 33 + n1]   + bl[96 + n1];
        float cc = creg1 * m;
        cc = sigm(F) * cc + sigm(I) * tanh_fast(G);
        creg1 = cc;
        h1v = sigm(O) * tanh_fast(cc);
      }
      uint32_t pk = (uint32_t)f2bf(h0v) | ((uint32_t)f2bf(h1v) << 16);
      uint32_t* hp = (uint32_t*)(hs + ((size_t)t * BSZ + bg + b_loc) * HID + win * 32 + n0);
      __hip_atomic_store(hp, pk, __ATOMIC_RELAXED, __HIP_MEMORY_SCOPE_AGENT);
      if (t == T_STEPS - 1) {
        size_t ob = (size_t)(bg + b_loc) * HID + win * 32 + n0;
        out[NROWS + ob]         = h0v;
        out[NROWS + ob + 1]     = h1v;
        out[2 * NROWS + ob]     = creg0;
        out[2 * NROWS + ob + 1] = creg1;
      }
    }
    // per-wave flag: own h stores drained at the LIC -> publish immediately
    asm volatile("s_waitcnt vmcnt(0)" ::: "memory");
    if ((tid & 63) == 0)
      __hip_atomic_store(flg + g * 64 + q * 16 + win, (uint32_t)(t + 1),
                         __ATOMIC_RELAXED, __HIP_MEMORY_SCOPE_AGENT);
  }
}

// ---------------------------------------------------------------------------
// Prep (merged): blocks 0..383 convert W1*ln_g | W2 fp32->bf16;
// blocks 384..511 compute u[n], v[n] (one wave per W1 row).
// ---------------------------------------------------------------------------
__global__ void prep_kernel(const float* __restrict__ W1, const float* __restrict__ W2,
                            const float* __restrict__ ln_g, const float* __restrict__ ln_b,
                            const float* __restrict__ b1, uint16_t* __restrict__ dst,
                            float* __restrict__ u, float* __restrict__ v)
{
  if (blockIdx.x < 384) {
    int idx = blockIdx.x * 256 + threadIdx.x;
    int i4 = idx * 4;
    float4 val;
    if (i4 < 262144) {
      val = *(const float4*)(W1 + i4);
      int c = i4 & 511;
      float4 gv = *(const float4*)(ln_g + c);
      val.x *= gv.x; val.y *= gv.y; val.z *= gv.z; val.w *= gv.w;
    } else {
      val = *(const float4*)(W2 + (i4 - 262144));
    }
    uint32_t lo = (uint32_t)f2bf(val.x) | ((uint32_t)f2bf(val.y) << 16);
    uint32_t hi = (uint32_t)f2bf(val.z) | ((uint32_t)f2bf(val.w) << 16);
    *(uint64_t*)(dst + i4) = (uint64_t)lo | ((uint64_t)hi << 32);
  } else {
    const int lane = threadIdx.x & 63;
    const int row  = (blockIdx.x - 384) * 4 + (threadIdx.x >> 6);
    const float* wp = W1 + (size_t)row * 512 + lane * 8;
    float4 w0 = *(const float4*)wp;
    float4 w1 = *(const float4*)(wp + 4);
    float4 g0 = *(const float4*)(ln_g + lane * 8);
    float4 g1 = *(const float4*)(ln_g + lane * 8 + 4);
    float4 b0 = *(const float4*)(ln_b + lane * 8);
    float4 b1v = *(const float4*)(ln_b + lane * 8 + 4);
    float su = b0.x * w0.x + b0.y * w0.y + b0.z * w0.z + b0.w * w0.w
             + b1v.x * w1.x + b1v.y * w1.y + b1v.z * w1.z + b1v.w * w1.w;
    float sv = g0.x * w0.x + g0.y * w0.y + g0.z * w0.z + g0.w * w0.w
             + g1.x * w1.x + g1.y * w1.y + g1.z * w1.z + g1.w * w1.w;
    #pragma unroll
    for (int o = 1; o < 64; o <<= 1) { su += __shfl_xor(su, o); sv += __shfl_xor(sv, o); }
    if (lane == 0) { u[row] = su + b1[row]; v[row] = sv; }
  }
}

// ---------------------------------------------------------------------------
// GEMM1: a1 = tanh(LN(h) @ W1g^T + ...), LN stats in-block, in-place over hs.
// No in-loop barriers: At is read-only after staging; C rows block-exclusive.
// ---------------------------------------------------------------------------
__global__ __launch_bounds__(256, 2) void gemm1_kernel(
    const uint16_t* __restrict__ Abase, const uint16_t* __restrict__ W,
    uint16_t* __restrict__ C,
    const float* __restrict__ uvec, const float* __restrict__ vvec)
{
  __shared__ uint16_t At[64 * 512];   // 65536 B
  __shared__ float sRS[64];
  __shared__ float sMRS[64];
  const int tid  = threadIdx.x;
  const int lane = tid & 63;
  const int wv   = tid >> 6;
  const size_t mbase = (size_t)blockIdx.x * 64;

  for (int r8 = 0; r8 < 16; ++r8) {
    int row = wv * 16 + r8;
    int sb  = (lane * 16) ^ ((row & 7) << 4);
    gll16(Abase + (mbase + row) * 512 + sb / 2, At + row * 512);
  }
  __syncthreads();

  // per-row LN stats from the staged tile (swizzle is bijective per row)
  for (int r8 = 0; r8 < 16; ++r8) {
    int row = wv * 16 + r8;
    bf16x8 v = *(const bf16x8*)((const char*)At +
                                ((row * 1024 + lane * 16) ^ ((row & 7) << 4)));
    float s = 0.f, s2 = 0.f;
    #pragma unroll
    for (int j = 0; j < 8; ++j) {
      float f = bf2f((uint16_t)v[j]);
      s += f; s2 += f * f;
    }
    #pragma unroll
    for (int o = 1; o < 64; o <<= 1) {
      s += __shfl_xor(s, o); s2 += __shfl_xor(s2, o);
    }
    if (lane == 0) {
      float mu  = s * (1.f / 512.f);
      float var = s2 * (1.f / 512.f) - mu * mu;
      float rs  = rsqrtf(var + 1e-5f);
      sRS[row]  = rs;
      sMRS[row] = mu * rs;
    }
  }
  __syncthreads();

  const int fr = lane & 15, kg = lane >> 4;
  const int mloc = (wv & 1) * 32;
  const int nhalf = (wv >> 1) * 64;

  for (int nt = 0; nt < 4; ++nt) {
    const int nbase = nt * 128 + nhalf;
    f32x4 vz = {0.f, 0.f, 0.f, 0.f};
    f32x4 acc[4][2];
    #pragma unroll
    for (int i = 0; i < 4; ++i) { acc[i][0] = vz; acc[i][1] = vz; }

    #pragma unroll 4
    for (int kb = 0; kb < 16; ++kb) {
      const int ke = kb * 32 + kg * 8;
      bf16x8 wf[4];
      #pragma unroll
      for (int i = 0; i < 4; ++i)
        wf[i] = *(const bf16x8*)(W + (size_t)(nbase + i * 16 + fr) * 512 + ke);
      bf16x8 af[2];
      #pragma unroll
      for (int j = 0; j < 2; ++j) {
        int mr = mloc + j * 16 + fr;
        af[j] = *(const bf16x8*)((const char*)At + ((mr * 1024 + ke * 2) ^ ((mr & 7) << 4)));
      }
      #pragma unroll
      for (int i = 0; i < 4; ++i)
        #pragma unroll
        for (int j = 0; j < 2; ++j)
          acc[i][j] = __builtin_amdgcn_mfma_f32_16x16x32_bf16(wf[i], af[j], acc[i][j], 0, 0, 0);
    }

    #pragma unroll
    for (int j = 0; j < 2; ++j) {
      int ml = mloc + j * 16 + fr;
      size_t m = mbase + ml;
      float rs = sRS[ml], mrs = sMRS[ml];
      #pragma unroll
      for (int i = 0; i < 4; ++i) {
        int n = nbase + i * 16 + kg * 4;
        float4 uu = *(const float4*)(uvec + n);
        float4 vv = *(const float4*)(vvec + n);
        float o0 = tanh_fast(rs * acc[i][j][0] - mrs * vv.x + uu.x);
        float o1 = tanh_fast(rs * acc[i][j][1] - mrs * vv.y + uu.y);
        float o2 = tanh_fast(rs * acc[i][j][2] - mrs * vv.z + uu.z);
        float o3 = tanh_fast(rs * acc[i][j][3] - mrs * vv.w + uu.w);
        uint32_t lo = (uint32_t)f2bf(o0) | ((uint32_t)f2bf(o1) << 16);
        uint32_t hi = (uint32_t)f2bf(o2) | ((uint32_t)f2bf(o3) << 16);
        *(uint64_t*)(C + m * 512 + n) = (uint64_t)lo | ((uint64_t)hi << 32);
      }
    }
  }
}

// ---------------------------------------------------------------------------
// GEMM2+GEMV fused: value[m] = sum_n tanh(a1[m,:]@W2[n,:]^T + b2[n])*Wv[n]+bv
// a2 never materialized.
// ---------------------------------------------------------------------------
__global__ __launch_bounds__(256, 2) void gemm2_value_kernel(
    const uint16_t* __restrict__ Abase, const uint16_t* __restrict__ W,
    const float* __restrict__ bias, const float* __restrict__ Wv,
    const float* __restrict__ bv, float* __restrict__ outv)
{
  __shared__ uint16_t At[64 * 512];   // 65536 B
  __shared__ float vred[2][64];
  const int tid  = threadIdx.x;
  const int lane = tid & 63;
  const int wv   = tid >> 6;
  const size_t mbase = (size_t)blockIdx.x * 64;

  for (int r8 = 0; r8 < 16; ++r8) {
    int row = wv * 16 + r8;
    int sb  = (lane * 16) ^ ((row & 7) << 4);
    gll16(Abase + (mbase + row) * 512 + sb / 2, At + row * 512);
  }
  __syncthreads();

  const int fr = lane & 15, kg = lane >> 4;
  const int mloc = (wv & 1) * 32;
  const int nhalf = (wv >> 1) * 64;

  float vpart0 = 0.f, vpart1 = 0.f;

  #pragma unroll
  for (int nt = 0; nt < 2; ++nt) {
    const int nbase = nt * 128 + nhalf;
    f32x4 vz = {0.f, 0.f, 0.f, 0.f};
    f32x4 acc[4][2];
    #pragma unroll
    for (int i = 0; i < 4; ++i) { acc[i][0] = vz; acc[i][1] = vz; }

    #pragma unroll 4
    for (int kb = 0; kb < 16; ++kb) {
      const int ke = kb * 32 + kg * 8;
      bf16x8 wf[4];
      #pragma unroll
      for (int i = 0; i < 4; ++i)
        wf[i] = *(const bf16x8*)(W + (size_t)(nbase + i * 16 + fr) * 512 + ke);
      bf16x8 af[2];
      #pragma unroll
      for (int j = 0; j < 2; ++j) {
        int mr = mloc + j * 16 + fr;
        af[j] = *(const bf16x8*)((const char*)At + ((mr * 1024 + ke * 2) ^ ((mr & 7) << 4)));
      }
      #pragma unroll
      for (int i = 0; i < 4; ++i)
        #pragma unroll
        for (int j = 0; j < 2; ++j)
          acc[i][j] = __builtin_amdgcn_mfma_f32_16x16x32_bf16(wf[i], af[j], acc[i][j], 0, 0, 0);
    }

    #pragma unroll
    for (int j = 0; j < 2; ++j) {
      float vp = 0.f;
      #pragma unroll
      for (int i = 0; i < 4; ++i) {
        int n = nbase + i * 16 + kg * 4;
        float4 bb  = *(const float4*)(bias + n);
        float4 wv4 = *(const float4*)(Wv + n);
        vp += tanh_fast(acc[i][j][0] + bb.x) * wv4.x
            + tanh_fast(acc[i][j][1] + bb.y) * wv4.y
            + tanh_fast(acc[i][j][2] + bb.z) * wv4.z
            + tanh_fast(acc[i][j][3] + bb.w) * wv4.w;
      }
      if (j == 0) vpart0 += vp; else vpart1 += vp;
    }
  }

  // reduce across kg lanes (fr fixed): lanes fr, fr+16, fr+32, fr+48
  vpart0 += __shfl_xor(vpart0, 16); vpart0 += __shfl_xor(vpart0, 32);
  vpart1 += __shfl_xor(vpart1, 16); vpart1 += __shfl_xor(vpart1, 32);
  if (kg == 0) {
    vred[wv >> 1][mloc + fr]      = vpart0;
    vred[wv >> 1][mloc + 16 + fr] = vpart1;
  }
  __syncthreads();
  if (tid < 64)
    outv[mbase + tid] = vred[0][tid] + vred[1][tid] + bv[0];
}

extern "C" void kernel_launch(void* const* d_in, const int* in_sizes, int n_in,
                              void* d_out, int out_size, void* d_ws, size_t ws_size,
                              hipStream_t stream)
{
  (void)in_sizes; (void)n_in;
  const float* x    = (const float*)d_in[0];
  const float* done = (const float*)d_in[1];
  const float* h0   = (const float*)d_in[2];
  const float* c0   = (const float*)d_in[3];
  const float* W_ih = (const float*)d_in[4];
  const float* W_hh = (const float*)d_in[5];
  const float* b_ih = (const float*)d_in[6];
  const float* b_hh = (const float*)d_in[7];
  const float* ln_g = (const float*)d_in[8];
  const float* ln_b = (const float*)d_in[9];
  const float* W1   = (const float*)d_in[10];
  const float* b1   = (const float*)d_in[11];
  const float* W2   = (const float*)d_in[12];
  const float* b2   = (const float*)d_in[13];
  const float* Wv   = (const float*)d_in[14];
  const float* bv   = (const float*)d_in[15];
  float* out = (float*)d_out;
  char* ws = (char*)d_ws;

  // ws layout (bytes):
  //   0        flg      4096     (16 groups x 64 per-wave flags, q-major)
  //   16384    wbf      786432   (bf16 W1g | W2)
  //   802816   u,v      4096     (512 f32 each)
  //   2097152  hs       134217728  (bf16 [T*B,512]; a1 in-place after gemm1)
  constexpr size_t NEED = 2097152ULL + 134217728ULL;
  if (ws_size < NEED) {
    hipMemsetAsync(d_out, 0, (size_t)out_size * 4, stream);
    return;
  }
  uint32_t* flg  = (uint32_t*)ws;
  uint16_t* wbf  = (uint16_t*)(ws + 16384);
  float*    uv_u = (float*)(ws + 802816);
  float*    uv_v = (float*)(ws + 802816 + 2048);
  uint16_t* hsb  = (uint16_t*)(ws + 2097152);

  hipMemsetAsync(ws, 0, 16384, stream);
  hipLaunchKernelGGL(prep_kernel, dim3(512), dim3(256), 0, stream,
                     W1, W2, ln_g, ln_b, b1, wbf, uv_u, uv_v);
  hipLaunchKernelGGL(lstm_kernel, dim3(256), dim3(256), 0, stream,
                     x, done, h0, c0, W_ih, W_hh, b_ih, b_hh, hsb, flg, out);
  // GEMM1: a1 = tanh(LN(h) @ W1g^T + ...), LN stats in-block, in-place over hs
  hipLaunchKernelGGL(gemm1_kernel, dim3(2048), dim3(256), 0, stream,
                     hsb, wbf, hsb, uv_u, uv_v);
  // GEMM2+GEMV fused: value directly, a2 never materialized
  hipLaunchKernelGGL(gemm2_value_kernel, dim3(2048), dim3(256), 0, stream,
                     hsb, wbf + 262144, b2, Wv, bv, out);
}

// Round 16
// 1843.369 us; speedup vs baseline: 2.1709x; 1.0004x over previous
//
#include <hip/hip_runtime.h>
#include <stdint.h>

// Problem constants
constexpr int T_STEPS = 512;
constexpr int BSZ     = 256;
constexpr int OBSD    = 64;
constexpr int HID     = 512;
constexpr int NROWS   = T_STEPS * BSZ;   // 131072

// LSTM partitioning: 16 groups x 16 WGs. Group owns 16 batch rows; WG owns
// 32 h-cols (all 4 gates).
constexpr int GROUPS = 16;
constexpr int WPG    = 16;
constexpr int BW     = 16;

typedef __attribute__((ext_vector_type(8))) short bf16x8;
typedef __attribute__((ext_vector_type(4))) float f32x4;

__device__ __forceinline__ float bf2f(uint16_t u) {
  union { uint32_t i; float f; } v; v.i = ((uint32_t)u) << 16; return v.f;
}
__device__ __forceinline__ uint16_t f2bf(float f) {
  union { float f; uint32_t i; } v; v.f = f;
  return (uint16_t)((v.i + 0x7FFFu + ((v.i >> 16) & 1u)) >> 16);
}
__device__ __forceinline__ uint64_t pack4(float a, float b, float c, float d) {
  uint32_t lo = (uint32_t)f2bf(a) | ((uint32_t)f2bf(b) << 16);
  uint32_t hi = (uint32_t)f2bf(c) | ((uint32_t)f2bf(d) << 16);
  return (uint64_t)lo | ((uint64_t)hi << 32);
}
__device__ __forceinline__ float sigm(float x) { return 1.f / (1.f + __expf(-x)); }
__device__ __forceinline__ float tanh_fast(float x) {
  float e = __expf(2.f * x);
  return 1.f - 2.f / (e + 1.f);
}

__device__ __forceinline__ void gll16(const void* g, void* l) {
  __builtin_amdgcn_global_load_lds(
      (const __attribute__((address_space(1))) uint32_t*)g,
      (__attribute__((address_space(3))) uint32_t*)l, 16, 0, 0);
}

// ---------------------------------------------------------------------------
// Persistent LSTM scan. 256 blocks x 256 threads, 1 block/CU.
// (Round-15 kernel verbatim -- proven 1.455 ms steady state.)
// x-contribution MFMAs issue before the flag poll (latency hides under
// detection); post-barrier MFMA phase is h-only (16 ks).
// Transport: h stores sc1->LIC; h loads plain cacheable (write-once per
// address per dispatch, read post-flag; start agent-acquire drops stale
// replay lines); flags agent-scope relaxed, q-major (single 64B poll read).
// ---------------------------------------------------------------------------
__global__ __launch_bounds__(256, 1) void lstm_kernel(
    const float* __restrict__ xin, const float* __restrict__ done,
    const float* __restrict__ h0, const float* __restrict__ c0,
    const float* __restrict__ W_ih, const float* __restrict__ W_hh,
    const float* __restrict__ b_ih, const float* __restrict__ b_hh,
    uint16_t* __restrict__ hs, uint32_t* __restrict__ flg,
    float* __restrict__ out)
{
  __shared__ char  Ab[16 * 1152];   // h rows only (first 1024B of each row)
  __shared__ float gl[4 * 528];     // [gate][16 rows][33 pad]
  __shared__ float bl[128];         // [gate][32 cols]

  const int wg   = blockIdx.x;
  const int g    = wg & 15;         // group
  const int win  = wg >> 4;         // slot within group -> col block win*32
  const int bg   = g * BW;
  const int tid  = threadIdx.x;
  const int lane = tid & 63;
  const int q    = tid >> 6;        // wave id == gate id

  __builtin_amdgcn_fence(__ATOMIC_ACQUIRE, "agent");

  bf16x8 bq0[18], bq1[18];
  {
    const int r0  = q * 512 + win * 32 + (lane & 15);
    const int r1  = r0 + 16;
    const int kg8 = (lane >> 4) * 8;
    #pragma unroll
    for (int ks = 0; ks < 18; ++ks) {
      const float* s0 = (ks < 16)
          ? (W_hh + (size_t)r0 * 512 + ks * 32 + kg8)
          : (W_ih + (size_t)r0 * 64 + (ks - 16) * 32 + kg8);
      const float* s1 = (ks < 16)
          ? (W_hh + (size_t)r1 * 512 + ks * 32 + kg8)
          : (W_ih + (size_t)r1 * 64 + (ks - 16) * 32 + kg8);
      float4 a0 = *(const float4*)s0;
      float4 a1 = *(const float4*)(s0 + 4);
      float4 b0 = *(const float4*)s1;
      float4 b1 = *(const float4*)(s1 + 4);
      bf16x8 va, vb;
      va[0] = (short)f2bf(a0.x); va[1] = (short)f2bf(a0.y);
      va[2] = (short)f2bf(a0.z); va[3] = (short)f2bf(a0.w);
      va[4] = (short)f2bf(a1.x); va[5] = (short)f2bf(a1.y);
      va[6] = (short)f2bf(a1.z); va[7] = (short)f2bf(a1.w);
      vb[0] = (short)f2bf(b0.x); vb[1] = (short)f2bf(b0.y);
      vb[2] = (short)f2bf(b0.z); vb[3] = (short)f2bf(b0.w);
      vb[4] = (short)f2bf(b1.x); vb[5] = (short)f2bf(b1.y);
      vb[6] = (short)f2bf(b1.z); vb[7] = (short)f2bf(b1.w);
      bq0[ks] = va; bq1[ks] = vb;
    }
  }
  if (tid < 128) {
    int gq = tid >> 5, c = tid & 31;
    int grow = gq * 512 + win * 32 + c;
    bl[tid] = b_ih[grow] + b_hh[grow];
  }

  const int b_loc = tid >> 4;
  const int n0    = (tid & 15) * 2;
  float creg0 = c0[(size_t)(bg + b_loc) * HID + win * 32 + n0];
  float creg1 = c0[(size_t)(bg + b_loc) * HID + win * 32 + n0 + 1];

  const int ar  = lane & 15;
  const int kg  = lane >> 4;
  const int rw  = q * 4;

  __syncthreads();

  for (int t = 0; t < T_STEPS; ++t) {
    float dvs[4];
    #pragma unroll
    for (int r8 = 0; r8 < 4; ++r8)
      dvs[r8] = done[(size_t)t * BSZ + bg + rw + r8];
    float dv_b = done[(size_t)t * BSZ + bg + b_loc];

    const float* xrow = xin + ((size_t)t * BSZ + bg + ar) * OBSD + kg * 8;
    float4 x0a = *(const float4*)(xrow);
    float4 x0b = *(const float4*)(xrow + 4);
    float4 x1a = *(const float4*)(xrow + 32);
    float4 x1b = *(const float4*)(xrow + 36);
    bf16x8 xk0, xk1;
    xk0[0] = (short)f2bf(x0a.x); xk0[1] = (short)f2bf(x0a.y);
    xk0[2] = (short)f2bf(x0a.z); xk0[3] = (short)f2bf(x0a.w);
    xk0[4] = (short)f2bf(x0b.x); xk0[5] = (short)f2bf(x0b.y);
    xk0[6] = (short)f2bf(x0b.z); xk0[7] = (short)f2bf(x0b.w);
    xk1[0] = (short)f2bf(x1a.x); xk1[1] = (short)f2bf(x1a.y);
    xk1[2] = (short)f2bf(x1a.z); xk1[3] = (short)f2bf(x1a.w);
    xk1[4] = (short)f2bf(x1b.x); xk1[5] = (short)f2bf(x1b.y);
    xk1[6] = (short)f2bf(x1b.z); xk1[7] = (short)f2bf(x1b.w);

    f32x4 ac0 = {0.f, 0.f, 0.f, 0.f};
    f32x4 ac1 = {0.f, 0.f, 0.f, 0.f};
    ac0 = __builtin_amdgcn_mfma_f32_16x16x32_bf16(xk0, bq0[16], ac0, 0, 0, 0);
    ac1 = __builtin_amdgcn_mfma_f32_16x16x32_bf16(xk0, bq1[16], ac1, 0, 0, 0);
    ac0 = __builtin_amdgcn_mfma_f32_16x16x32_bf16(xk1, bq0[17], ac0, 0, 0, 0);
    ac1 = __builtin_amdgcn_mfma_f32_16x16x32_bf16(xk1, bq1[17], ac1, 0, 0, 0);

    if (t > 0) {
      for (;;) {
        uint32_t f = (lane < WPG)
            ? __hip_atomic_load(flg + g * 64 + q * 16 + lane,
                                __ATOMIC_RELAXED, __HIP_MEMORY_SCOPE_AGENT)
            : 0xFFFFFFFFu;
        if (__all((int)(f >= (uint32_t)t))) break;
      }
      __builtin_amdgcn_fence(__ATOMIC_ACQUIRE, "workgroup");
    }

    if (t == 0) {
      #pragma unroll
      for (int r8 = 0; r8 < 4; ++r8) {
        int r = rw + r8;
        uint64_t v0 = 0, v1 = 0;
        if (dvs[r8] <= 0.5f) {
          const float* hp = h0 + (size_t)(bg + r) * HID;
          float4 ha = *(const float4*)(hp + lane * 4);
          float4 hb = *(const float4*)(hp + 256 + lane * 4);
          v0 = pack4(ha.x, ha.y, ha.z, ha.w);
          v1 = pack4(hb.x, hb.y, hb.z, hb.w);
        }
        *(uint64_t*)(Ab + ((r * 1152 + lane * 8) ^ ((r & 7) << 4))) = v0;
        *(uint64_t*)(Ab + ((r * 1152 + 512 + lane * 8) ^ ((r & 7) << 4))) = v1;
      }
    } else {
      #pragma unroll
      for (int r8 = 0; r8 < 4; ++r8) {
        int r = rw + r8;
        const uint4* hrow =
            (const uint4*)(hs + ((size_t)(t - 1) * BSZ + bg + r) * 512);
        uint4 v = hrow[lane];
        if (dvs[r8] > 0.5f) { v.x = 0; v.y = 0; v.z = 0; v.w = 0; }
        *(uint4*)(Ab + ((r * 1152 + lane * 16) ^ ((r & 7) << 4))) = v;
      }
    }
    __syncthreads();

    #pragma unroll
    for (int ks = 0; ks < 16; ++ks) {
      int kb = ks * 64 + kg * 16;
      bf16x8 a = *(const bf16x8*)(Ab + ((ar * 1152 + kb) ^ ((ar & 7) << 4)));
      ac0 = __builtin_amdgcn_mfma_f32_16x16x32_bf16(a, bq0[ks], ac0, 0, 0, 0);
      ac1 = __builtin_amdgcn_mfma_f32_16x16x32_bf16(a, bq1[ks], ac1, 0, 0, 0);
    }
    {
      int c  = lane & 15;
      int rb = (lane >> 4) * 4;
      #pragma unroll
      for (int r = 0; r < 4; ++r) {
        gl[q * 528 + (rb + r) * 33 + c]      = ac0[r];
        gl[q * 528 + (rb + r) * 33 + 16 + c] = ac1[r];
      }
    }
    __syncthreads();

    {
      float m = dv_b > 0.5f ? 0.f : 1.f;
      float h0v, h1v;
      {
        float I = gl[b_loc * 33 + n0]          + bl[n0];
        float F = gl[528 + b_loc * 33 + n0]    + bl[32 + n0];
        float G = gl[1056 + b_loc * 33 + n0]   + bl[64 + n0];
        float O = gl[1584 + b_loc * 33 + n0]   + bl[96 + n0];
        float cc = creg0 * m;
        cc = sigm(F) * cc + sigm(I) * tanh_fast(G);
        creg0 = cc;
        h0v = sigm(O) * tanh_fast(cc);
      }
      {
        int n1 = n0 + 1;
        float I = gl[b_loc * 33 + n1]          + bl[n1];
        float F = gl[528 + b_loc * 33 + n1]    + bl[32 + n1];
        float G = gl[1056 + b_loc * 33 + n1]   + bl[64 + n1];
        float O = gl[1584 + b_loc * 33 + n1]   + bl[96 + n1];
        float cc = creg1 * m;
        cc = sigm(F) * cc + sigm(I) * tanh_fast(G);
        creg1 = cc;
        h1v = sigm(O) * tanh_fast(cc);
      }
      uint32_t pk = (uint32_t)f2bf(h0v) | ((uint32_t)f2bf(h1v) << 16);
      uint32_t* hp = (uint32_t*)(hs + ((size_t)t * BSZ + bg + b_loc) * HID + win * 32 + n0);
      __hip_atomic_store(hp, pk, __ATOMIC_RELAXED, __HIP_MEMORY_SCOPE_AGENT);
      if (t == T_STEPS - 1) {
        size_t ob = (size_t)(bg + b_loc) * HID + win * 32 + n0;
        out[NROWS + ob]         = h0v;
        out[NROWS + ob + 1]     = h1v;
        out[2 * NROWS + ob]     = creg0;
        out[2 * NROWS + ob + 1] = creg1;
      }
    }
    asm volatile("s_waitcnt vmcnt(0)" ::: "memory");
    if ((tid & 63) == 0)
      __hip_atomic_store(flg + g * 64 + q * 16 + win, (uint32_t)(t + 1),
                         __ATOMIC_RELAXED, __HIP_MEMORY_SCOPE_AGENT);
  }
}

// ---------------------------------------------------------------------------
// Prep (merged): blocks 0..383 convert W1*ln_g | W2 fp32->bf16;
// blocks 384..511 compute u[n], v[n] (one wave per W1 row).
// ---------------------------------------------------------------------------
__global__ void prep_kernel(const float* __restrict__ W1, const float* __restrict__ W2,
                            const float* __restrict__ ln_g, const float* __restrict__ ln_b,
                            const float* __restrict__ b1, uint16_t* __restrict__ dst,
                            float* __restrict__ u, float* __restrict__ v)
{
  if (blockIdx.x < 384) {
    int idx = blockIdx.x * 256 + threadIdx.x;
    int i4 = idx * 4;
    float4 val;
    if (i4 < 262144) {
      val = *(const float4*)(W1 + i4);
      int c = i4 & 511;
      float4 gv = *(const float4*)(ln_g + c);
      val.x *= gv.x; val.y *= gv.y; val.z *= gv.z; val.w *= gv.w;
    } else {
      val = *(const float4*)(W2 + (i4 - 262144));
    }
    uint32_t lo = (uint32_t)f2bf(val.x) | ((uint32_t)f2bf(val.y) << 16);
    uint32_t hi = (uint32_t)f2bf(val.z) | ((uint32_t)f2bf(val.w) << 16);
    *(uint64_t*)(dst + i4) = (uint64_t)lo | ((uint64_t)hi << 32);
  } else {
    const int lane = threadIdx.x & 63;
    const int row  = (blockIdx.x - 384) * 4 + (threadIdx.x >> 6);
    const float* wp = W1 + (size_t)row * 512 + lane * 8;
    float4 w0 = *(const float4*)wp;
    float4 w1 = *(const float4*)(wp + 4);
    float4 g0 = *(const float4*)(ln_g + lane * 8);
    float4 g1 = *(const float4*)(ln_g + lane * 8 + 4);
    float4 b0 = *(const float4*)(ln_b + lane * 8);
    float4 b1v = *(const float4*)(ln_b + lane * 8 + 4);
    float su = b0.x * w0.x + b0.y * w0.y + b0.z * w0.z + b0.w * w0.w
             + b1v.x * w1.x + b1v.y * w1.y + b1v.z * w1.z + b1v.w * w1.w;
    float sv = g0.x * w0.x + g0.y * w0.y + g0.z * w0.z + g0.w * w0.w
             + g1.x * w1.x + g1.y * w1.y + g1.z * w1.z + g1.w * w1.w;
    #pragma unroll
    for (int o = 1; o < 64; o <<= 1) { su += __shfl_xor(su, o); sv += __shfl_xor(sv, o); }
    if (lane == 0) { u[row] = su + b1[row]; v[row] = sv; }
  }
}

// ---------------------------------------------------------------------------
// Fully fused tail: per 64-row tile --
//   stage h -> LN stats -> GEMM1 (a1 kept packed in regs, 32 x u64) ->
//   barrier -> a1 overwrites the At LDS buffer (same swizzled layout) ->
//   barrier -> GEMM2 from LDS -> dot with Wv -> value out.
// a1 NEVER touches global memory; hs read exactly once.
// ---------------------------------------------------------------------------
__global__ __launch_bounds__(256, 2) void tail_fused_kernel(
    const uint16_t* __restrict__ Abase, const uint16_t* __restrict__ W1b,
    const uint16_t* __restrict__ W2b,
    const float* __restrict__ uvec, const float* __restrict__ vvec,
    const float* __restrict__ b2, const float* __restrict__ Wv,
    const float* __restrict__ bv, float* __restrict__ outv)
{
  __shared__ uint16_t At[64 * 512];   // 65536 B: h tile, then a1 tile
  __shared__ float sRS[64];
  __shared__ float sMRS[64];
  __shared__ float vred[2][64];
  const int tid  = threadIdx.x;
  const int lane = tid & 63;
  const int wv   = tid >> 6;
  const size_t mbase = (size_t)blockIdx.x * 64;

  for (int r8 = 0; r8 < 16; ++r8) {
    int row = wv * 16 + r8;
    int sb  = (lane * 16) ^ ((row & 7) << 4);
    gll16(Abase + (mbase + row) * 512 + sb / 2, At + row * 512);
  }
  __syncthreads();

  // per-row LN stats from the staged tile (swizzle bijective per row)
  for (int r8 = 0; r8 < 16; ++r8) {
    int row = wv * 16 + r8;
    bf16x8 v = *(const bf16x8*)((const char*)At +
                                ((row * 1024 + lane * 16) ^ ((row & 7) << 4)));
    float s = 0.f, s2 = 0.f;
    #pragma unroll
    for (int j = 0; j < 8; ++j) {
      float f = bf2f((uint16_t)v[j]);
      s += f; s2 += f * f;
    }
    #pragma unroll
    for (int o = 1; o < 64; o <<= 1) {
      s += __shfl_xor(s, o); s2 += __shfl_xor(s2, o);
    }
    if (lane == 0) {
      float mu  = s * (1.f / 512.f);
      float var = s2 * (1.f / 512.f) - mu * mu;
      float rs  = rsqrtf(var + 1e-5f);
      sRS[row]  = rs;
      sMRS[row] = mu * rs;
    }
  }
  __syncthreads();

  const int fr = lane & 15, kg = lane >> 4;
  const int mloc = (wv & 1) * 32;
  const int nhalf = (wv >> 1) * 64;

  // ---- GEMM1: a1 tile kept in registers (packed bf16, 32 x u64) ----
  uint64_t a1p[4][2][4];   // [nt][j][i]
  #pragma unroll
  for (int nt = 0; nt < 4; ++nt) {
    const int nbase = nt * 128 + nhalf;
    f32x4 vz = {0.f, 0.f, 0.f, 0.f};
    f32x4 acc[4][2];
    #pragma unroll
    for (int i = 0; i < 4; ++i) { acc[i][0] = vz; acc[i][1] = vz; }

    #pragma unroll 4
    for (int kb = 0; kb < 16; ++kb) {
      const int ke = kb * 32 + kg * 8;
      bf16x8 wf[4];
      #pragma unroll
      for (int i = 0; i < 4; ++i)
        wf[i] = *(const bf16x8*)(W1b + (size_t)(nbase + i * 16 + fr) * 512 + ke);
      bf16x8 af[2];
      #pragma unroll
      for (int j = 0; j < 2; ++j) {
        int mr = mloc + j * 16 + fr;
        af[j] = *(const bf16x8*)((const char*)At + ((mr * 1024 + ke * 2) ^ ((mr & 7) << 4)));
      }
      #pragma unroll
      for (int i = 0; i < 4; ++i)
        #pragma unroll
        for (int j = 0; j < 2; ++j)
          acc[i][j] = __builtin_amdgcn_mfma_f32_16x16x32_bf16(wf[i], af[j], acc[i][j], 0, 0, 0);
    }

    #pragma unroll
    for (int j = 0; j < 2; ++j) {
      int ml = mloc + j * 16 + fr;
      float rs = sRS[ml], mrs = sMRS[ml];
      #pragma unroll
      for (int i = 0; i < 4; ++i) {
        int n = nbase + i * 16 + kg * 4;
        float4 uu = *(const float4*)(uvec + n);
        float4 vv = *(const float4*)(vvec + n);
        a1p[nt][j][i] = pack4(
            tanh_fast(rs * acc[i][j][0] - mrs * vv.x + uu.x),
            tanh_fast(rs * acc[i][j][1] - mrs * vv.y + uu.y),
            tanh_fast(rs * acc[i][j][2] - mrs * vv.z + uu.z),
            tanh_fast(rs * acc[i][j][3] - mrs * vv.w + uu.w));
      }
    }
  }
  __syncthreads();   // everyone done READING the h tile

  // ---- a1 -> LDS (same swizzled layout the K-loop reads) ----
  #pragma unroll
  for (int nt = 0; nt < 4; ++nt) {
    const int nbase = nt * 128 + nhalf;
    #pragma unroll
    for (int j = 0; j < 2; ++j) {
      int mr = mloc + j * 16 + fr;
      #pragma unroll
      for (int i = 0; i < 4; ++i) {
        int cb = (nbase + i * 16 + kg * 4) * 2;    // byte col offset (8B-aligned)
        *(uint64_t*)((char*)At + ((mr * 1024 + cb) ^ ((mr & 7) << 4))) = a1p[nt][j][i];
      }
    }
  }
  __syncthreads();   // a1 tile fully in LDS

  // ---- GEMM2 + value: K=512 over a1, N=256, dot with Wv ----
  float vpart0 = 0.f, vpart1 = 0.f;
  #pragma unroll
  for (int nt = 0; nt < 2; ++nt) {
    const int nbase = nt * 128 + nhalf;
    f32x4 vz = {0.f, 0.f, 0.f, 0.f};
    f32x4 acc[4][2];
    #pragma unroll
    for (int i = 0; i < 4; ++i) { acc[i][0] = vz; acc[i][1] = vz; }

    #pragma unroll 4
    for (int kb = 0; kb < 16; ++kb) {
      const int ke = kb * 32 + kg * 8;
      bf16x8 wf[4];
      #pragma unroll
      for (int i = 0; i < 4; ++i)
        wf[i] = *(const bf16x8*)(W2b + (size_t)(nbase + i * 16 + fr) * 512 + ke);
      bf16x8 af[2];
      #pragma unroll
      for (int j = 0; j < 2; ++j) {
        int mr = mloc + j * 16 + fr;
        af[j] = *(const bf16x8*)((const char*)At + ((mr * 1024 + ke * 2) ^ ((mr & 7) << 4)));
      }
      #pragma unroll
      for (int i = 0; i < 4; ++i)
        #pragma unroll
        for (int j = 0; j < 2; ++j)
          acc[i][j] = __builtin_amdgcn_mfma_f32_16x16x32_bf16(wf[i], af[j], acc[i][j], 0, 0, 0);
    }

    #pragma unroll
    for (int j = 0; j < 2; ++j) {
      float vp = 0.f;
      #pragma unroll
      for (int i = 0; i < 4; ++i) {
        int n = nbase + i * 16 + kg * 4;
        float4 bb  = *(const float4*)(b2 + n);
        float4 wv4 = *(const float4*)(Wv + n);
        vp += tanh_fast(acc[i][j][0] + bb.x) * wv4.x
            + tanh_fast(acc[i][j][1] + bb.y) * wv4.y
            + tanh_fast(acc[i][j][2] + bb.z) * wv4.z
            + tanh_fast(acc[i][j][3] + bb.w) * wv4.w;
      }
      if (j == 0) vpart0 += vp; else vpart1 += vp;
    }
  }

  vpart0 += __shfl_xor(vpart0, 16); vpart0 += __shfl_xor(vpart0, 32);
  vpart1 += __shfl_xor(vpart1, 16); vpart1 += __shfl_xor(vpart1, 32);
  if (kg == 0) {
    vred[wv >> 1][mloc + fr]      = vpart0;
    vred[wv >> 1][mloc + 16 + fr] = vpart1;
  }
  __syncthreads();
  if (tid < 64)
    outv[mbase + tid] = vred[0][tid] + vred[1][tid] + bv[0];
}

extern "C" void kernel_launch(void* const* d_in, const int* in_sizes, int n_in,
                              void* d_out, int out_size, void* d_ws, size_t ws_size,
                              hipStream_t stream)
{
  (void)in_sizes; (void)n_in;
  const float* x    = (const float*)d_in[0];
  const float* done = (const float*)d_in[1];
  const float* h0   = (const float*)d_in[2];
  const float* c0   = (const float*)d_in[3];
  const float* W_ih = (const float*)d_in[4];
  const float* W_hh = (const float*)d_in[5];
  const float* b_ih = (const float*)d_in[6];
  const float* b_hh = (const float*)d_in[7];
  const float* ln_g = (const float*)d_in[8];
  const float* ln_b = (const float*)d_in[9];
  const float* W1   = (const float*)d_in[10];
  const float* b1   = (const float*)d_in[11];
  const float* W2   = (const float*)d_in[12];
  const float* b2   = (const float*)d_in[13];
  const float* Wv   = (const float*)d_in[14];
  const float* bv   = (const float*)d_in[15];
  float* out = (float*)d_out;
  char* ws = (char*)d_ws;

  // ws layout (bytes):
  //   0        flg      4096     (16 groups x 64 per-wave flags, q-major)
  //   16384    wbf      786432   (bf16 W1g | W2)
  //   802816   u,v      4096     (512 f32 each)
  //   2097152  hs       134217728  (bf16 [T*B,512])
  constexpr size_t NEED = 2097152ULL + 134217728ULL;
  if (ws_size < NEED) {
    hipMemsetAsync(d_out, 0, (size_t)out_size * 4, stream);
    return;
  }
  uint32_t* flg  = (uint32_t*)ws;
  uint16_t* wbf  = (uint16_t*)(ws + 16384);
  float*    uv_u = (float*)(ws + 802816);
  float*    uv_v = (float*)(ws + 802816 + 2048);
  uint16_t* hsb  = (uint16_t*)(ws + 2097152);

  hipMemsetAsync(ws, 0, 16384, stream);
  hipLaunchKernelGGL(prep_kernel, dim3(512), dim3(256), 0, stream,
                     W1, W2, ln_g, ln_b, b1, wbf, uv_u, uv_v);
  hipLaunchKernelGGL(lstm_kernel, dim3(256), dim3(256), 0, stream,
                     x, done, h0, c0, W_ih, W_hh, b_ih, b_hh, hsb, flg, out);
  // Fully fused tail: LN + GEMM1 + GEMM2 + value (a1 never hits global)
  hipLaunchKernelGGL(tail_fused_kernel, dim3(2048), dim3(256), 0, stream,
                     hsb, wbf, wbf + 262144, uv_u, uv_v, b2, Wv, bv, out);
}